// Round 8
// baseline (560.015 us; speedup 1.0000x reference)
//
#include <hip/hip_runtime.h>
#include <stdint.h>

#define BATCH 4
#define CH    256
#define NTOK  4096
#define KSEL  409          // int(0.1 * 4096)

typedef unsigned short u16;
typedef unsigned int   u32;
typedef unsigned long long u64;

typedef __attribute__((ext_vector_type(8))) _Float16 half8;
typedef __attribute__((ext_vector_type(4))) _Float16 half4;
typedef __attribute__((ext_vector_type(4))) float f32x4;
typedef __attribute__((ext_vector_type(4))) u32 u32x4;
typedef __attribute__((ext_vector_type(2))) u32 u32x2;
typedef __attribute__((ext_vector_type(4))) float fl4;

// ---------------- helpers ----------------
__device__ inline u16 h2u(_Float16 h){ u16 u; __builtin_memcpy(&u,&h,2); return u; }
// monotone float<->uint key transform (ascending)
__device__ inline float keyinv(u32 k){ u32 v=(k&0x80000000u)?(k^0x80000000u):~k; return __uint_as_float(v); }
__device__ inline void gload16(const void* g, void* l){
  __builtin_amdgcn_global_load_lds((const __attribute__((address_space(1))) u32*)g,
                                   (__attribute__((address_space(3))) u32*)l, 16, 0, 0);
}

// ---------------- phase -1: W split ----------------
__global__ __launch_bounds__(256) void wsplit_kernel(
    const float* __restrict__ Wq, const float* __restrict__ Wk,
    const float* __restrict__ Wv, u16* __restrict__ W3h, u16* __restrict__ W3l)
{
  const int p = blockIdx.y;
  const float* W = (p==0)? Wq : (p==1)? Wk : Wv;
  const int idx = (blockIdx.x*256 + threadIdx.x) * 4;
  fl4 v = *(const fl4*)(W + idx);
  u32x2 vh, vl;
  #pragma unroll
  for (int q=0;q<2;q++) {
    _Float16 h0=(_Float16)v[q*2], h1=(_Float16)v[q*2+1];
    _Float16 l0=(_Float16)(v[q*2]-(float)h0), l1=(_Float16)(v[q*2+1]-(float)h1);
    vh[q] = (u32)h2u(h0) | ((u32)h2u(h1)<<16);
    vl[q] = (u32)h2u(l0) | ((u32)h2u(l1)<<16);
  }
  *(u32x2*)(W3h + p*CH*CH + idx) = vh;
  *(u32x2*)(W3l + p*CH*CH + idx) = vl;
}

// ---------------- phase 0a: x transpose + split ----------------
__global__ __launch_bounds__(256) void xsplit_kernel(
    const float* __restrict__ x, u16* __restrict__ xTh, u16* __restrict__ xTl)
{
  __shared__ float lds[64][65];
  const int tid = threadIdx.x;
  const int n0 = blockIdx.x << 6;
  const int c0 = blockIdx.y << 6;
  const int b  = blockIdx.z;
  const float* xb = x + (size_t)b*CH*NTOK;

  #pragma unroll
  for (int i=0;i<16;i++) {
    int c_l = (tid>>6) + (i<<2);
    int n_l = tid & 63;
    lds[c_l][n_l] = xb[(size_t)(c0+c_l)*NTOK + n0 + n_l];
  }
  __syncthreads();
  u16* oh = xTh + (size_t)b*NTOK*CH;
  u16* ol = xTl + (size_t)b*NTOK*CH;
  #pragma unroll
  for (int i=0;i<16;i++) {
    int n_l = (tid>>6) + (i<<2);
    int c_l = tid & 63;
    float v = lds[c_l][n_l];
    _Float16 h = (_Float16)v;
    _Float16 l = (_Float16)(v - (float)h);
    size_t o = (size_t)(n0+n_l)*CH + c0 + c_l;
    oh[o] = h2u(h);
    ol[o] = h2u(l);
  }
}

// ---------------- phase 0b: QKV projection GEMM ----------------
__global__ __launch_bounds__(256) void proj_gemm(
    const u16* __restrict__ xTh, const u16* __restrict__ xTl,
    const u16* __restrict__ W3h, const u16* __restrict__ W3l,
    u16* __restrict__ Qh, u16* __restrict__ Kh, u16* __restrict__ Vc)
{
  __shared__ __align__(16) short lds[4*128*64];   // ah, al, bh, bl (16KB each)
  short* lds_ah = lds;
  short* lds_al = lds + 128*64;
  short* lds_bh = lds + 2*128*64;
  short* lds_bl = lds + 3*128*64;

  const int tid  = threadIdx.x;
  const int lane = tid & 63;
  const int wave = tid >> 6;
  const int wm = wave >> 1, wn = wave & 1;
  const int brow = blockIdx.x << 7;     // token tile
  const int bcol = blockIdx.y << 7;     // out-channel tile
  const int z = blockIdx.z;             // b*3 + p
  const int b = z / 3, p = z - 3*b;

  const u16* Agh = xTh + ((size_t)b*NTOK + brow)*CH;
  const u16* Agl = xTl + ((size_t)b*NTOK + brow)*CH;
  const u16* Bgh = W3h + (size_t)p*CH*CH + (size_t)bcol*CH;
  const u16* Bgl = W3l + (size_t)p*CH*CH + (size_t)bcol*CH;

  f32x4 acc[4][4];
  #pragma unroll
  for (int i=0;i<4;i++)
    #pragma unroll
    for (int j=0;j<4;j++) acc[i][j] = (f32x4)0.f;

  const int sr    = tid >> 3;
  const int sslot = tid & 7;

  for (int kt=0; kt<4; kt++) {
    #pragma unroll
    for (int c=0;c<4;c++) {
      int r  = (c<<5) + sr;
      int ss = sslot ^ (r & 7);
      size_t goff = (size_t)r*CH + (kt<<6) + (ss<<3);
      int dst = (c<<12) + (wave<<10);
      gload16(Agh + goff, (char*)lds_ah + dst);
      gload16(Agl + goff, (char*)lds_al + dst);
      gload16(Bgh + goff, (char*)lds_bh + dst);
      gload16(Bgl + goff, (char*)lds_bl + dst);
    }
    __syncthreads();
    #pragma unroll
    for (int ks=0;ks<2;ks++) {
      half8 ah[4], al[4], bh[4], bl[4];
      const int kg = lane >> 4;
      const int rl = lane & 15;
      #pragma unroll
      for (int t=0;t<4;t++) {
        int ar = (wm<<6) + (t<<4) + rl;
        int slot = (ks<<2) + kg;
        int ao = ar*64 + ((slot ^ (ar&7))<<3);
        ah[t] = *(const half8*)&lds_ah[ao];
        al[t] = *(const half8*)&lds_al[ao];
        int br = (wn<<6) + (t<<4) + rl;
        int bo = br*64 + ((slot ^ (br&7))<<3);
        bh[t] = *(const half8*)&lds_bh[bo];
        bl[t] = *(const half8*)&lds_bl[bo];
      }
      #pragma unroll
      for (int mt=0;mt<4;mt++)
        #pragma unroll
        for (int nt=0;nt<4;nt++) {
          acc[mt][nt] = __builtin_amdgcn_mfma_f32_16x16x32_f16(ah[mt], bh[nt], acc[mt][nt], 0,0,0);
          acc[mt][nt] = __builtin_amdgcn_mfma_f32_16x16x32_f16(ah[mt], bl[nt], acc[mt][nt], 0,0,0);
          acc[mt][nt] = __builtin_amdgcn_mfma_f32_16x16x32_f16(al[mt], bh[nt], acc[mt][nt], 0,0,0);
        }
    }
    __syncthreads();
  }

  const int rl = lane & 15, rg = lane >> 4;
  if (p < 2) {
    u16* oh = ((p==0)? Qh : Kh) + (size_t)b*NTOK*CH;
    #pragma unroll
    for (int mt=0;mt<4;mt++) {
      #pragma unroll
      for (int nt=0;nt<4;nt++) {
        int n = brow + (wm<<6) + (mt<<4) + (rg<<2);
        int c = bcol + (wn<<6) + (nt<<4) + rl;
        #pragma unroll
        for (int r=0;r<4;r++)
          oh[(size_t)(n+r)*CH + c] = h2u((_Float16)acc[mt][nt][r]);
      }
    }
  } else {
    // V: transpose in LDS -> store channel-major Vc[b][d][n] coalesced
    u16* ldsT = (u16*)lds;                 // [128][136] u16
    #pragma unroll
    for (int mt=0;mt<4;mt++) {
      #pragma unroll
      for (int nt=0;nt<4;nt++) {
        int n_l = (wm<<6) + (mt<<4) + (rg<<2);
        int c_l = (wn<<6) + (nt<<4) + rl;
        half4 hv;
        #pragma unroll
        for (int r=0;r<4;r++) hv[r] = (_Float16)acc[mt][nt][r];
        *(half4*)&ldsT[c_l*136 + n_l] = hv;
      }
    }
    __syncthreads();
    u16* ov = Vc + (size_t)b*CH*NTOK + (size_t)bcol*NTOK + brow;
    #pragma unroll
    for (int i=0;i<32;i++) {
      int d_l = (tid>>6) + (i<<2);
      u32 v = *(const u32*)&ldsT[d_l*136 + (lane<<1)];
      *(u32*)(ov + (size_t)d_l*NTOK + (lane<<1)) = v;
    }
  }
}

// ---------------- phase 1: S = Q*K^T / 16 (one batch), hi-only fp16 ----------------
__global__ __launch_bounds__(256) void score_kernel(
    const u16* __restrict__ Qh, const u16* __restrict__ Kh,
    float* __restrict__ S, int b)
{
  __shared__ __align__(16) short lds_a[128*64];
  __shared__ __align__(16) short lds_b[128*64];
  const int tid  = threadIdx.x;
  const int lane = tid & 63;
  const int wave = tid >> 6;
  const int wm = wave >> 1, wn = wave & 1;
  const int brow = blockIdx.x << 7, bcol = blockIdx.y << 7;

  const u16* Ag = Qh + ((size_t)b*NTOK + brow)*CH;
  const u16* Bg = Kh + ((size_t)b*NTOK + bcol)*CH;

  f32x4 acc[4][4];
  #pragma unroll
  for (int i=0;i<4;i++)
    #pragma unroll
    for (int j=0;j<4;j++) acc[i][j] = (f32x4)0.f;

  const int sr    = tid >> 3;
  const int sslot = tid & 7;

  for (int kt=0; kt<4; kt++) {
    #pragma unroll
    for (int c=0;c<4;c++) {
      int r  = (c<<5) + sr;
      int ss = sslot ^ (r & 7);
      size_t goff = (size_t)r*CH + (kt<<6) + (ss<<3);
      int dst = (c<<12) + (wave<<10);
      gload16(Ag + goff, (char*)lds_a + dst);
      gload16(Bg + goff, (char*)lds_b + dst);
    }
    __syncthreads();
    #pragma unroll
    for (int ks=0;ks<2;ks++) {
      half8 af[4], bf[4];
      const int kg = lane >> 4;
      const int rl = lane & 15;
      #pragma unroll
      for (int t=0;t<4;t++) {
        int ar = (wm<<6) + (t<<4) + rl;
        int slot = (ks<<2) + kg;
        af[t] = *(const half8*)&lds_a[ar*64 + ((slot ^ (ar&7))<<3)];
        int br = (wn<<6) + (t<<4) + rl;
        bf[t] = *(const half8*)&lds_b[br*64 + ((slot ^ (br&7))<<3)];
      }
      #pragma unroll
      for (int mt=0;mt<4;mt++)
        #pragma unroll
        for (int nt=0;nt<4;nt++)
          acc[mt][nt] = __builtin_amdgcn_mfma_f32_16x16x32_f16(af[mt], bf[nt], acc[mt][nt], 0,0,0);
    }
    __syncthreads();
  }

  const int rl = lane & 15, rg = lane >> 4;
  #pragma unroll
  for (int mt=0;mt<4;mt++) {
    #pragma unroll
    for (int nt=0;nt<4;nt++) {
      int row = brow + (wm<<6) + (mt<<4) + (rg<<2);
      int col = bcol + (wn<<6) + (nt<<4) + rl;
      #pragma unroll
      for (int r=0;r<4;r++)
        S[(size_t)(row+r)*NTOK + col] = acc[mt][nt][r] * 0.0625f;
    }
  }
}

// ---------------- phase 2: exact per-row top-KSEL -> dense fp16 weight row ----------------
// one wave per row; 4096 keys held in wave VGPRs (64/lane). __launch_bounds__(256,1)
// lifts the default occupancy-driven VGPR cap that was spilling key[] to scratch
// (rounds 5-7 were all scratch-L2-BW-bound at VGPR_Count<=76).
// Exact KSEL-th-largest key via MSB-first bit descend, per-lane VALU counts +
// one butterfly reduce per bit. Tie inclusion in index order == jax.lax.top_k.
__global__ __launch_bounds__(256, 1) void select_kernel(
    const float* __restrict__ S, u16* __restrict__ Wd)
{
  const int lane = threadIdx.x & 63;
  const int wave = threadIdx.x >> 6;
  const int row  = (blockIdx.x << 2) + wave;
  const float* Srow = S + (size_t)row * NTOK;

  u32 key[64];
  float m = -3.4e38f;
  #pragma unroll
  for (int ch=0; ch<64; ch++) {
    float s = Srow[(ch<<6) + lane];              // element index = ch*64 + lane
    m = fmaxf(m, s);
    u32 u = __float_as_uint(s);
    key[ch] = (u & 0x80000000u) ? ~u : (u | 0x80000000u);
  }
  #pragma unroll
  for (int off=32; off; off>>=1) m = fmaxf(m, __shfl_xor(m, off, 64));

  // T = exact KSEL-th largest key: MSB-first bit descend, VALU-count per lane.
  u32 prefix = 0;
  for (int bit=31; bit>=0; --bit) {
    const u32 cand = prefix | (1u << bit);
    u32 c = 0;
    #pragma unroll
    for (int ch=0; ch<64; ch++)
      c += (key[ch] >= cand) ? 1u : 0u;          // v_cmp + addc, registers only
    #pragma unroll
    for (int off=32; off; off>>=1) c += __shfl_xor(c, off, 64);
    if (c >= KSEL) prefix = cand;                // wave-uniform after reduce
  }
  const u32 tkey = prefix;
  const float tf = keyinv(tkey);

  // strictly-greater count (same VALU pattern)
  u32 cgt = 0;
  #pragma unroll
  for (int ch=0; ch<64; ch++)
    cgt += (key[ch] > tkey) ? 1u : 0u;
  #pragma unroll
  for (int off=32; off; off>>=1) cgt += __shfl_xor(cgt, off, 64);
  const int krem = KSEL - (int)cgt;              // >= 1 threshold ties to include

  // softmax denominator over the selected set
  float z = 0.f;
  #pragma unroll
  for (int ch=0; ch<64; ch++)
    if (key[ch] > tkey) z += __expf(keyinv(key[ch]) - m);
  #pragma unroll
  for (int off=32; off; off>>=1) z += __shfl_xor(z, off, 64);
  float Z = z + (float)krem * __expf(tf - m);
  float invZ = 1.f / Z;

  // dense weight row (w for selected, 0 elsewhere), fp16; ties in index order
  u16* wrow = Wd + (size_t)row * NTOK;
  const u64 ltmask = (1ull << lane) - 1ull;
  int eqbase = 0;
  #pragma unroll
  for (int ch=0; ch<64; ch++) {
    u32 u = key[ch];
    bool eq = (u == tkey);
    u64 eqm = __ballot(eq);
    bool sel = (u > tkey) || (eq && (eqbase + __popcll(eqm & ltmask)) < krem);
    float w = sel ? (__expf(keyinv(u) - m) * invZ) : 0.f;
    wrow[(ch<<6) + lane] = h2u((_Float16)w);
    eqbase += __popcll(eqm);
  }
}

// ---------------- phase 3: dense PV GEMM ----------------
// out^T[c,n] = sum_k Vc[c,k] * Wd[n,k].  128(M=ch) x 64(N=tok) tiles, K=NTOK.
__global__ __launch_bounds__(256) void pv_gemm(
    const u16* __restrict__ Vc, const u16* __restrict__ Wd,
    float* __restrict__ out, int b_base, size_t wstride)
{
  __shared__ __align__(16) short lds_a[128*64];   // 16 KB
  __shared__ __align__(16) short lds_b[64*64];    //  8 KB
  const int tid  = threadIdx.x;
  const int lane = tid & 63;
  const int wave = tid >> 6;
  const int wm = wave >> 1, wn = wave & 1;
  const int b    = b_base + blockIdx.z;
  const int brow = blockIdx.x << 7;      // channel tile (0/128)
  const int bcol = blockIdx.y << 6;      // token tile (64-wide)

  const u16* Ag = Vc + (size_t)b*CH*NTOK + (size_t)brow*NTOK;
  const u16* Bg = Wd + (size_t)blockIdx.z*wstride + (size_t)bcol*NTOK;

  f32x4 acc[4][2];
  #pragma unroll
  for (int i=0;i<4;i++)
    #pragma unroll
    for (int j=0;j<2;j++) acc[i][j] = (f32x4)0.f;

  const int sr    = tid >> 3;
  const int sslot = tid & 7;

  for (int kt=0; kt<64; kt++) {
    #pragma unroll
    for (int c=0;c<4;c++) {
      int r  = (c<<5) + sr;
      int ss = sslot ^ (r & 7);
      size_t goff = (size_t)r*NTOK + (kt<<6) + (ss<<3);
      gload16(Ag + goff, (char*)lds_a + (c<<12) + (wave<<10));
    }
    #pragma unroll
    for (int c=0;c<2;c++) {
      int r  = (c<<5) + sr;
      int ss = sslot ^ (r & 7);
      size_t goff = (size_t)r*NTOK + (kt<<6) + (ss<<3);
      gload16(Bg + goff, (char*)lds_b + (c<<12) + (wave<<10));
    }
    __syncthreads();
    #pragma unroll
    for (int ks=0;ks<2;ks++) {
      half8 af[4], bf[2];
      const int kg = lane >> 4;
      const int rl = lane & 15;
      const int slot = (ks<<2) + kg;
      #pragma unroll
      for (int t=0;t<4;t++) {
        int ar = (wm<<6) + (t<<4) + rl;
        af[t] = *(const half8*)&lds_a[ar*64 + ((slot ^ (ar&7))<<3)];
      }
      #pragma unroll
      for (int t=0;t<2;t++) {
        int br = (wn<<5) + (t<<4) + rl;
        bf[t] = *(const half8*)&lds_b[br*64 + ((slot ^ (br&7))<<3)];
      }
      #pragma unroll
      for (int mt=0;mt<4;mt++)
        #pragma unroll
        for (int nt=0;nt<2;nt++)
          acc[mt][nt] = __builtin_amdgcn_mfma_f32_16x16x32_f16(af[mt], bf[nt], acc[mt][nt], 0,0,0);
    }
    __syncthreads();
  }

  float* ob = out + (size_t)b*CH*NTOK;
  const int rl = lane & 15, rg = lane >> 4;
  #pragma unroll
  for (int mt=0;mt<4;mt++) {
    #pragma unroll
    for (int nt=0;nt<2;nt++) {
      int row = brow + (wm<<6) + (mt<<4) + (rg<<2);   // channel
      int col = bcol + (wn<<5) + (nt<<4) + rl;        // token
      #pragma unroll
      for (int r=0;r<4;r++)
        ob[(size_t)(row+r)*NTOK + col] = acc[mt][nt][r];
    }
  }
}

// ---------------- launcher ----------------
extern "C" void kernel_launch(void* const* d_in, const int* in_sizes, int n_in,
                              void* d_out, int out_size, void* d_ws, size_t ws_size,
                              hipStream_t stream)
{
  (void)in_sizes; (void)n_in; (void)out_size;
  const float* x  = (const float*)d_in[0];
  const float* Wq = (const float*)d_in[1];
  const float* Wk = (const float*)d_in[2];
  const float* Wv = (const float*)d_in[3];
  float* out = (float*)d_out;

  char* ws = (char*)d_ws;
  size_t off = 0;
  const size_t plane = (size_t)BATCH*NTOK*CH*2;       // 8.4 MB fp16 plane
  const size_t NN    = (size_t)NTOK*NTOK;             // 16.8M elements
  u16* Qh = (u16*)(ws + off); off += plane;
  u16* Kh = (u16*)(ws + off); off += plane;
  u16* Vc = (u16*)(ws + off); off += plane;
  u16* W3h = (u16*)(ws + off); off += (size_t)3*CH*CH*2;
  u16* W3l = (u16*)(ws + off); off += (size_t)3*CH*CH*2;
  // xT planes live only until proj_gemm completes; Wd overlaps them afterwards.
  const size_t xt_base = off;
  u16* xTh = (u16*)(ws + xt_base);
  u16* xTl = (u16*)(ws + xt_base + plane);
  const size_t fullW_need = xt_base + (size_t)BATCH*NN*2 + NN*4;   // ~227 MiB
  const bool fullW = ws_size >= fullW_need;
  u16* Wd = (u16*)(ws + xt_base);
  float* S = (float*)(ws + xt_base + (fullW ? (size_t)BATCH*NN*2 : NN*2));

  wsplit_kernel<<<dim3(64,3), 256, 0, stream>>>(Wq, Wk, Wv, W3h, W3l);
  xsplit_kernel<<<dim3(64,4,4), 256, 0, stream>>>(x, xTh, xTl);
  proj_gemm<<<dim3(32,2,12), 256, 0, stream>>>(xTh, xTl, W3h, W3l, Qh, Kh, Vc);

  if (fullW) {
    for (int b=0; b<BATCH; b++) {
      score_kernel<<<dim3(32,32), 256, 0, stream>>>(Qh, Kh, S, b);
      select_kernel<<<1024, 256, 0, stream>>>(S, Wd + (size_t)b*NN);
    }
    pv_gemm<<<dim3(2,64,4), 256, 0, stream>>>(Vc, Wd, out, 0, NN);
  } else {
    for (int b=0; b<BATCH; b++) {
      score_kernel<<<dim3(32,32), 256, 0, stream>>>(Qh, Kh, S, b);
      select_kernel<<<1024, 256, 0, stream>>>(S, Wd);
      pv_gemm<<<dim3(2,64,1), 256, 0, stream>>>(Vc, Wd, out, b, 0);
    }
  }
}

// Round 9
// 399.772 us; speedup vs baseline: 1.4008x; 1.4008x over previous
//
#include <hip/hip_runtime.h>
#include <stdint.h>

#define BATCH 4
#define CH    256
#define NTOK  4096
#define KSEL  409          // int(0.1 * 4096)

typedef unsigned short u16;
typedef unsigned int   u32;
typedef unsigned long long u64;

typedef __attribute__((ext_vector_type(8))) _Float16 half8;
typedef __attribute__((ext_vector_type(4))) _Float16 half4;
typedef __attribute__((ext_vector_type(4))) float f32x4;
typedef __attribute__((ext_vector_type(4))) u32 u32x4;
typedef __attribute__((ext_vector_type(2))) u32 u32x2;
typedef __attribute__((ext_vector_type(4))) float fl4;

// ---------------- helpers ----------------
__device__ inline u16 h2u(_Float16 h){ u16 u; __builtin_memcpy(&u,&h,2); return u; }
// monotone float<->uint key transform (ascending)
__device__ inline float keyinv(u32 k){ u32 v=(k&0x80000000u)?(k^0x80000000u):~k; return __uint_as_float(v); }
__device__ inline void gload16(const void* g, void* l){
  __builtin_amdgcn_global_load_lds((const __attribute__((address_space(1))) u32*)g,
                                   (__attribute__((address_space(3))) u32*)l, 16, 0, 0);
}

// ---------------- phase -1: W split ----------------
__global__ __launch_bounds__(256) void wsplit_kernel(
    const float* __restrict__ Wq, const float* __restrict__ Wk,
    const float* __restrict__ Wv, u16* __restrict__ W3h, u16* __restrict__ W3l)
{
  const int p = blockIdx.y;
  const float* W = (p==0)? Wq : (p==1)? Wk : Wv;
  const int idx = (blockIdx.x*256 + threadIdx.x) * 4;
  fl4 v = *(const fl4*)(W + idx);
  u32x2 vh, vl;
  #pragma unroll
  for (int q=0;q<2;q++) {
    _Float16 h0=(_Float16)v[q*2], h1=(_Float16)v[q*2+1];
    _Float16 l0=(_Float16)(v[q*2]-(float)h0), l1=(_Float16)(v[q*2+1]-(float)h1);
    vh[q] = (u32)h2u(h0) | ((u32)h2u(h1)<<16);
    vl[q] = (u32)h2u(l0) | ((u32)h2u(l1)<<16);
  }
  *(u32x2*)(W3h + p*CH*CH + idx) = vh;
  *(u32x2*)(W3l + p*CH*CH + idx) = vl;
}

// ---------------- phase 0a: x transpose + split ----------------
__global__ __launch_bounds__(256) void xsplit_kernel(
    const float* __restrict__ x, u16* __restrict__ xTh, u16* __restrict__ xTl)
{
  __shared__ float lds[64][65];
  const int tid = threadIdx.x;
  const int n0 = blockIdx.x << 6;
  const int c0 = blockIdx.y << 6;
  const int b  = blockIdx.z;
  const float* xb = x + (size_t)b*CH*NTOK;

  #pragma unroll
  for (int i=0;i<16;i++) {
    int c_l = (tid>>6) + (i<<2);
    int n_l = tid & 63;
    lds[c_l][n_l] = xb[(size_t)(c0+c_l)*NTOK + n0 + n_l];
  }
  __syncthreads();
  u16* oh = xTh + (size_t)b*NTOK*CH;
  u16* ol = xTl + (size_t)b*NTOK*CH;
  #pragma unroll
  for (int i=0;i<16;i++) {
    int n_l = (tid>>6) + (i<<2);
    int c_l = tid & 63;
    float v = lds[c_l][n_l];
    _Float16 h = (_Float16)v;
    _Float16 l = (_Float16)(v - (float)h);
    size_t o = (size_t)(n0+n_l)*CH + c0 + c_l;
    oh[o] = h2u(h);
    ol[o] = h2u(l);
  }
}

// ---------------- phase 0b: QKV projection GEMM ----------------
__global__ __launch_bounds__(256) void proj_gemm(
    const u16* __restrict__ xTh, const u16* __restrict__ xTl,
    const u16* __restrict__ W3h, const u16* __restrict__ W3l,
    u16* __restrict__ Qh, u16* __restrict__ Kh, u16* __restrict__ Vc)
{
  __shared__ __align__(16) short lds[4*128*64];   // ah, al, bh, bl (16KB each)
  short* lds_ah = lds;
  short* lds_al = lds + 128*64;
  short* lds_bh = lds + 2*128*64;
  short* lds_bl = lds + 3*128*64;

  const int tid  = threadIdx.x;
  const int lane = tid & 63;
  const int wave = tid >> 6;
  const int wm = wave >> 1, wn = wave & 1;
  const int brow = blockIdx.x << 7;     // token tile
  const int bcol = blockIdx.y << 7;     // out-channel tile
  const int z = blockIdx.z;             // b*3 + p
  const int b = z / 3, p = z - 3*b;

  const u16* Agh = xTh + ((size_t)b*NTOK + brow)*CH;
  const u16* Agl = xTl + ((size_t)b*NTOK + brow)*CH;
  const u16* Bgh = W3h + (size_t)p*CH*CH + (size_t)bcol*CH;
  const u16* Bgl = W3l + (size_t)p*CH*CH + (size_t)bcol*CH;

  f32x4 acc[4][4];
  #pragma unroll
  for (int i=0;i<4;i++)
    #pragma unroll
    for (int j=0;j<4;j++) acc[i][j] = (f32x4)0.f;

  const int sr    = tid >> 3;
  const int sslot = tid & 7;

  for (int kt=0; kt<4; kt++) {
    #pragma unroll
    for (int c=0;c<4;c++) {
      int r  = (c<<5) + sr;
      int ss = sslot ^ (r & 7);
      size_t goff = (size_t)r*CH + (kt<<6) + (ss<<3);
      int dst = (c<<12) + (wave<<10);
      gload16(Agh + goff, (char*)lds_ah + dst);
      gload16(Agl + goff, (char*)lds_al + dst);
      gload16(Bgh + goff, (char*)lds_bh + dst);
      gload16(Bgl + goff, (char*)lds_bl + dst);
    }
    __syncthreads();
    #pragma unroll
    for (int ks=0;ks<2;ks++) {
      half8 ah[4], al[4], bh[4], bl[4];
      const int kg = lane >> 4;
      const int rl = lane & 15;
      #pragma unroll
      for (int t=0;t<4;t++) {
        int ar = (wm<<6) + (t<<4) + rl;
        int slot = (ks<<2) + kg;
        int ao = ar*64 + ((slot ^ (ar&7))<<3);
        ah[t] = *(const half8*)&lds_ah[ao];
        al[t] = *(const half8*)&lds_al[ao];
        int br = (wn<<6) + (t<<4) + rl;
        int bo = br*64 + ((slot ^ (br&7))<<3);
        bh[t] = *(const half8*)&lds_bh[bo];
        bl[t] = *(const half8*)&lds_bl[bo];
      }
      #pragma unroll
      for (int mt=0;mt<4;mt++)
        #pragma unroll
        for (int nt=0;nt<4;nt++) {
          acc[mt][nt] = __builtin_amdgcn_mfma_f32_16x16x32_f16(ah[mt], bh[nt], acc[mt][nt], 0,0,0);
          acc[mt][nt] = __builtin_amdgcn_mfma_f32_16x16x32_f16(ah[mt], bl[nt], acc[mt][nt], 0,0,0);
          acc[mt][nt] = __builtin_amdgcn_mfma_f32_16x16x32_f16(al[mt], bh[nt], acc[mt][nt], 0,0,0);
        }
    }
    __syncthreads();
  }

  const int rl = lane & 15, rg = lane >> 4;
  if (p < 2) {
    u16* oh = ((p==0)? Qh : Kh) + (size_t)b*NTOK*CH;
    #pragma unroll
    for (int mt=0;mt<4;mt++) {
      #pragma unroll
      for (int nt=0;nt<4;nt++) {
        int n = brow + (wm<<6) + (mt<<4) + (rg<<2);
        int c = bcol + (wn<<6) + (nt<<4) + rl;
        #pragma unroll
        for (int r=0;r<4;r++)
          oh[(size_t)(n+r)*CH + c] = h2u((_Float16)acc[mt][nt][r]);
      }
    }
  } else {
    // V: transpose in LDS -> store channel-major Vc[b][d][n] coalesced
    u16* ldsT = (u16*)lds;                 // [128][136] u16
    #pragma unroll
    for (int mt=0;mt<4;mt++) {
      #pragma unroll
      for (int nt=0;nt<4;nt++) {
        int n_l = (wm<<6) + (mt<<4) + (rg<<2);
        int c_l = (wn<<6) + (nt<<4) + rl;
        half4 hv;
        #pragma unroll
        for (int r=0;r<4;r++) hv[r] = (_Float16)acc[mt][nt][r];
        *(half4*)&ldsT[c_l*136 + n_l] = hv;
      }
    }
    __syncthreads();
    u16* ov = Vc + (size_t)b*CH*NTOK + (size_t)bcol*NTOK + brow;
    #pragma unroll
    for (int i=0;i<32;i++) {
      int d_l = (tid>>6) + (i<<2);
      u32 v = *(const u32*)&ldsT[d_l*136 + (lane<<1)];
      *(u32*)(ov + (size_t)d_l*NTOK + (lane<<1)) = v;
    }
  }
}

// ---------------- phase 1: S = Q*K^T / 16 (one batch), hi-only fp16 ----------------
__global__ __launch_bounds__(256) void score_kernel(
    const u16* __restrict__ Qh, const u16* __restrict__ Kh,
    float* __restrict__ S, int b)
{
  __shared__ __align__(16) short lds_a[128*64];
  __shared__ __align__(16) short lds_b[128*64];
  const int tid  = threadIdx.x;
  const int lane = tid & 63;
  const int wave = tid >> 6;
  const int wm = wave >> 1, wn = wave & 1;
  const int brow = blockIdx.x << 7, bcol = blockIdx.y << 7;

  const u16* Ag = Qh + ((size_t)b*NTOK + brow)*CH;
  const u16* Bg = Kh + ((size_t)b*NTOK + bcol)*CH;

  f32x4 acc[4][4];
  #pragma unroll
  for (int i=0;i<4;i++)
    #pragma unroll
    for (int j=0;j<4;j++) acc[i][j] = (f32x4)0.f;

  const int sr    = tid >> 3;
  const int sslot = tid & 7;

  for (int kt=0; kt<4; kt++) {
    #pragma unroll
    for (int c=0;c<4;c++) {
      int r  = (c<<5) + sr;
      int ss = sslot ^ (r & 7);
      size_t goff = (size_t)r*CH + (kt<<6) + (ss<<3);
      int dst = (c<<12) + (wave<<10);
      gload16(Ag + goff, (char*)lds_a + dst);
      gload16(Bg + goff, (char*)lds_b + dst);
    }
    __syncthreads();
    #pragma unroll
    for (int ks=0;ks<2;ks++) {
      half8 af[4], bf[4];
      const int kg = lane >> 4;
      const int rl = lane & 15;
      #pragma unroll
      for (int t=0;t<4;t++) {
        int ar = (wm<<6) + (t<<4) + rl;
        int slot = (ks<<2) + kg;
        af[t] = *(const half8*)&lds_a[ar*64 + ((slot ^ (ar&7))<<3)];
        int br = (wn<<6) + (t<<4) + rl;
        bf[t] = *(const half8*)&lds_b[br*64 + ((slot ^ (br&7))<<3)];
      }
      #pragma unroll
      for (int mt=0;mt<4;mt++)
        #pragma unroll
        for (int nt=0;nt<4;nt++)
          acc[mt][nt] = __builtin_amdgcn_mfma_f32_16x16x32_f16(af[mt], bf[nt], acc[mt][nt], 0,0,0);
    }
    __syncthreads();
  }

  const int rl = lane & 15, rg = lane >> 4;
  #pragma unroll
  for (int mt=0;mt<4;mt++) {
    #pragma unroll
    for (int nt=0;nt<4;nt++) {
      int row = brow + (wm<<6) + (mt<<4) + (rg<<2);
      int col = bcol + (wn<<6) + (nt<<4) + rl;
      #pragma unroll
      for (int r=0;r<4;r++)
        S[(size_t)(row+r)*NTOK + col] = acc[mt][nt][r] * 0.0625f;
    }
  }
}

// ---------------- phase 2: exact per-row top-KSEL -> dense fp16 weight row ----------------
// one wave per row, 64 keys/lane in VGPRs. Radix histogram (8-bit LDS, per-wave, as the
// measured-fastest round-5 variant) but: typically only 2 passes, then the <=64-key
// threshold bucket is compacted to one reg/lane and finished with a wave bitonic sort.
// Exact fallback to passes 3/4 when the bucket is degenerate (>64 equal-prefix keys).
// Tie inclusion in index order == jax.lax.top_k (fast path when all ties included).
__global__ __launch_bounds__(256) void select_kernel(
    const float* __restrict__ S, u16* __restrict__ Wd)
{
  __shared__ __align__(16) u32 hist[4][256];
  __shared__ __align__(16) u32 cbuf[4][64];
  __shared__ u32 ccnt[4];
  const int lane = threadIdx.x & 63;
  const int wave = threadIdx.x >> 6;
  const int row  = (blockIdx.x << 2) + wave;
  const float* Srow = S + (size_t)row * NTOK;

  u32 key[64];
  float m = -3.4e38f;
  #pragma unroll
  for (int ch=0; ch<64; ch++) {
    float s = Srow[(ch<<6) + lane];              // element index = ch*64 + lane
    m = fmaxf(m, s);
    u32 u = __float_as_uint(s);
    key[ch] = (u & 0x80000000u) ? ~u : (u | 0x80000000u);
  }
  #pragma unroll
  for (int off=32; off; off>>=1) m = fmaxf(m, __shfl_xor(m, off, 64));

  // radix passes (8 bits each), early-exit when threshold bucket fits one reg/lane
  u32 prefix = 0, krem = KSEL, cb = NTOK, matchmask = 0;
  int shift = 24;
  for (int pass=0; pass<4; ++pass) {
    #pragma unroll
    for (int i=0;i<4;i++) hist[wave][(i<<6)+lane] = 0u;
    __asm__ volatile("s_waitcnt lgkmcnt(0)" ::: "memory");
    #pragma unroll
    for (int ch=0; ch<64; ch++) {
      u32 kk = key[ch];
      if (((kk ^ prefix) & matchmask) == 0u)
        atomicAdd(&hist[wave][(kk >> shift) & 255u], 1u);
    }
    __asm__ volatile("s_waitcnt lgkmcnt(0)" ::: "memory");
    u32x4 h = *(const u32x4*)&hist[wave][lane<<2];
    u32 tot = h[0]+h[1]+h[2]+h[3];
    u32 sfx = tot;
    #pragma unroll
    for (int off=1; off<64; off<<=1) {
      u32 v = __shfl_down(sfx, off, 64);
      if (lane + off < 64) sfx += v;
    }
    u32 s3 = (sfx - tot) + h[3];
    u32 s2 = s3 + h[2];
    u32 s1 = s2 + h[1];
    u32 s0 = s1 + h[0];
    u32 s4 = s3 - h[3];
    u32 kr = krem;
    u32 enc = 0;
    if (s0 >= kr && s1 < kr) enc = ((u32)((lane<<2)+0)<<22) | (h[0]<<9) | (kr - s1);
    if (s1 >= kr && s2 < kr) enc = ((u32)((lane<<2)+1)<<22) | (h[1]<<9) | (kr - s2);
    if (s2 >= kr && s3 < kr) enc = ((u32)((lane<<2)+2)<<22) | (h[2]<<9) | (kr - s3);
    if (s3 >= kr && s4 < kr) enc = ((u32)((lane<<2)+3)<<22) | (h[3]<<9) | (kr - s4);
    #pragma unroll
    for (int off=32; off; off>>=1) { u32 o = __shfl_xor(enc, off, 64); enc = (o>enc)? o:enc; }
    prefix |= (enc >> 22) << shift;
    cb     = (enc >> 9) & 0x1FFFu;
    krem   = enc & 0x1FFu;
    if (cb <= 64u || shift == 0) break;
    matchmask = 0xFFFFFFFFu << shift;
    shift -= 8;
  }

  u32 tkey;
  if (cb <= 64u && shift > 0) {
    // compact the threshold bucket, then wave bitonic sort (descending)
    if (lane == 0) ccnt[wave] = 0u;
    __asm__ volatile("s_waitcnt lgkmcnt(0)" ::: "memory");
    const u32 cmask = 0xFFFFFFFFu << shift;
    #pragma unroll
    for (int ch=0; ch<64; ch++) {
      u32 kk = key[ch];
      if (((kk ^ prefix) & cmask) == 0u) {
        u32 pos = atomicAdd(&ccnt[wave], 1u);
        cbuf[wave][pos & 63u] = kk;
      }
    }
    __asm__ volatile("s_waitcnt lgkmcnt(0)" ::: "memory");
    u32 v = (lane < (int)cb) ? cbuf[wave][lane] : 0u;
    #pragma unroll
    for (int k=2; k<=64; k<<=1) {
      #pragma unroll
      for (int j=k>>1; j>0; j>>=1) {
        u32 o = (u32)__shfl_xor((int)v, j, 64);
        bool dirDesc = ((lane & k) == 0);
        bool takeMax = (((lane & j) == 0) == dirDesc);
        u32 mx = v > o ? v : o;
        u32 mn = v > o ? o : v;
        v = takeMax ? mx : mn;
      }
    }
    tkey = (u32)__shfl((int)v, (int)krem - 1, 64);
  } else {
    tkey = prefix;     // full 32-bit descend completed (degenerate path)
  }
  const float tf = keyinv(tkey);

  // tie statistics
  u32 gtc = 0;
  u64 eqm_l = 0;
  #pragma unroll
  for (int ch=0; ch<64; ch++) {
    gtc += (key[ch] > tkey) ? 1u : 0u;
    if (key[ch] == tkey) eqm_l |= (1ull << ch);
  }
  #pragma unroll
  for (int off=32; off; off>>=1) gtc += __shfl_xor(gtc, off, 64);
  u32 eqc = (u32)__popcll(eqm_l);
  #pragma unroll
  for (int off=32; off; off>>=1) eqc += __shfl_xor(eqc, off, 64);
  const u32 kremT = KSEL - gtc;          // #threshold ties to include, >= 1

  u16* wrow = Wd + (size_t)row * NTOK;
  if (eqc == kremT) {
    // fast path (overwhelmingly common): all ties included -> sel = key >= tkey
    u64 selb = 0;
    float z = 0.f;
    #pragma unroll
    for (int ch=0; ch<64; ch++) {
      u32 kk = key[ch];
      float e = __expf(keyinv(kk) - m);
      if (kk >= tkey) { z += e; selb |= (1ull << ch); }
      key[ch] = __float_as_uint(e);      // cache exp, key no longer needed
    }
    #pragma unroll
    for (int off=32; off; off>>=1) z += __shfl_xor(z, off, 64);
    float invZ = 1.f / z;
    #pragma unroll
    for (int ch=0; ch<64; ch++) {
      float w = ((selb >> ch) & 1ull) ? __uint_as_float(key[ch]) * invZ : 0.f;
      wrow[(ch<<6) + lane] = h2u((_Float16)w);
    }
  } else {
    // slow path: ballot-ordered tie inclusion (index order), exact
    float z = 0.f;
    #pragma unroll
    for (int ch=0; ch<64; ch++)
      if (key[ch] > tkey) z += __expf(keyinv(key[ch]) - m);
    #pragma unroll
    for (int off=32; off; off>>=1) z += __shfl_xor(z, off, 64);
    float Z = z + (float)kremT * __expf(tf - m);
    float invZ = 1.f / Z;
    const u64 ltmask = (1ull << lane) - 1ull;
    int eqbase = 0;
    #pragma unroll
    for (int ch=0; ch<64; ch++) {
      u32 u = key[ch];
      bool eq = (u == tkey);
      u64 eqm = __ballot(eq);
      bool sel = (u > tkey) || (eq && (eqbase + __popcll(eqm & ltmask)) < (int)kremT);
      float w = sel ? (__expf(keyinv(u) - m) * invZ) : 0.f;
      wrow[(ch<<6) + lane] = h2u((_Float16)w);
      eqbase += __popcll(eqm);
    }
  }
}

// ---------------- phase 3: dense PV GEMM ----------------
// out^T[c,n] = sum_k Vc[c,k] * Wd[n,k].  128(M=ch) x 64(N=tok) tiles, K=NTOK.
__global__ __launch_bounds__(256) void pv_gemm(
    const u16* __restrict__ Vc, const u16* __restrict__ Wd,
    float* __restrict__ out, int b_base, size_t wstride)
{
  __shared__ __align__(16) short lds_a[128*64];   // 16 KB
  __shared__ __align__(16) short lds_b[64*64];    //  8 KB
  const int tid  = threadIdx.x;
  const int lane = tid & 63;
  const int wave = tid >> 6;
  const int wm = wave >> 1, wn = wave & 1;
  const int b    = b_base + blockIdx.z;
  const int brow = blockIdx.x << 7;      // channel tile (0/128)
  const int bcol = blockIdx.y << 6;      // token tile (64-wide)

  const u16* Ag = Vc + (size_t)b*CH*NTOK + (size_t)brow*NTOK;
  const u16* Bg = Wd + (size_t)blockIdx.z*wstride + (size_t)bcol*NTOK;

  f32x4 acc[4][2];
  #pragma unroll
  for (int i=0;i<4;i++)
    #pragma unroll
    for (int j=0;j<2;j++) acc[i][j] = (f32x4)0.f;

  const int sr    = tid >> 3;
  const int sslot = tid & 7;

  for (int kt=0; kt<64; kt++) {
    #pragma unroll
    for (int c=0;c<4;c++) {
      int r  = (c<<5) + sr;
      int ss = sslot ^ (r & 7);
      size_t goff = (size_t)r*NTOK + (kt<<6) + (ss<<3);
      gload16(Ag + goff, (char*)lds_a + (c<<12) + (wave<<10));
    }
    #pragma unroll
    for (int c=0;c<2;c++) {
      int r  = (c<<5) + sr;
      int ss = sslot ^ (r & 7);
      size_t goff = (size_t)r*NTOK + (kt<<6) + (ss<<3);
      gload16(Bg + goff, (char*)lds_b + (c<<12) + (wave<<10));
    }
    __syncthreads();
    #pragma unroll
    for (int ks=0;ks<2;ks++) {
      half8 af[4], bf[2];
      const int kg = lane >> 4;
      const int rl = lane & 15;
      const int slot = (ks<<2) + kg;
      #pragma unroll
      for (int t=0;t<4;t++) {
        int ar = (wm<<6) + (t<<4) + rl;
        af[t] = *(const half8*)&lds_a[ar*64 + ((slot ^ (ar&7))<<3)];
      }
      #pragma unroll
      for (int t=0;t<2;t++) {
        int br = (wn<<5) + (t<<4) + rl;
        bf[t] = *(const half8*)&lds_b[br*64 + ((slot ^ (br&7))<<3)];
      }
      #pragma unroll
      for (int mt=0;mt<4;mt++)
        #pragma unroll
        for (int nt=0;nt<2;nt++)
          acc[mt][nt] = __builtin_amdgcn_mfma_f32_16x16x32_f16(af[mt], bf[nt], acc[mt][nt], 0,0,0);
    }
    __syncthreads();
  }

  float* ob = out + (size_t)b*CH*NTOK;
  const int rl = lane & 15, rg = lane >> 4;
  #pragma unroll
  for (int mt=0;mt<4;mt++) {
    #pragma unroll
    for (int nt=0;nt<2;nt++) {
      int row = brow + (wm<<6) + (mt<<4) + (rg<<2);   // channel
      int col = bcol + (wn<<5) + (nt<<4) + rl;        // token
      #pragma unroll
      for (int r=0;r<4;r++)
        ob[(size_t)(row+r)*NTOK + col] = acc[mt][nt][r];
    }
  }
}

// ---------------- launcher ----------------
extern "C" void kernel_launch(void* const* d_in, const int* in_sizes, int n_in,
                              void* d_out, int out_size, void* d_ws, size_t ws_size,
                              hipStream_t stream)
{
  (void)in_sizes; (void)n_in; (void)out_size;
  const float* x  = (const float*)d_in[0];
  const float* Wq = (const float*)d_in[1];
  const float* Wk = (const float*)d_in[2];
  const float* Wv = (const float*)d_in[3];
  float* out = (float*)d_out;

  char* ws = (char*)d_ws;
  size_t off = 0;
  const size_t plane = (size_t)BATCH*NTOK*CH*2;       // 8.4 MB fp16 plane
  const size_t NN    = (size_t)NTOK*NTOK;             // 16.8M elements
  u16* Qh = (u16*)(ws + off); off += plane;
  u16* Kh = (u16*)(ws + off); off += plane;
  u16* Vc = (u16*)(ws + off); off += plane;
  u16* W3h = (u16*)(ws + off); off += (size_t)3*CH*CH*2;
  u16* W3l = (u16*)(ws + off); off += (size_t)3*CH*CH*2;
  // xT planes live only until proj_gemm completes; Wd overlaps them afterwards.
  const size_t xt_base = off;
  u16* xTh = (u16*)(ws + xt_base);
  u16* xTl = (u16*)(ws + xt_base + plane);
  const size_t fullW_need = xt_base + (size_t)BATCH*NN*2 + NN*4;   // ~227 MiB
  const bool fullW = ws_size >= fullW_need;
  u16* Wd = (u16*)(ws + xt_base);
  float* S = (float*)(ws + xt_base + (fullW ? (size_t)BATCH*NN*2 : NN*2));

  wsplit_kernel<<<dim3(64,3), 256, 0, stream>>>(Wq, Wk, Wv, W3h, W3l);
  xsplit_kernel<<<dim3(64,4,4), 256, 0, stream>>>(x, xTh, xTl);
  proj_gemm<<<dim3(32,2,12), 256, 0, stream>>>(xTh, xTl, W3h, W3l, Qh, Kh, Vc);

  if (fullW) {
    for (int b=0; b<BATCH; b++) {
      score_kernel<<<dim3(32,32), 256, 0, stream>>>(Qh, Kh, S, b);
      select_kernel<<<1024, 256, 0, stream>>>(S, Wd + (size_t)b*NN);
    }
    pv_gemm<<<dim3(2,64,4), 256, 0, stream>>>(Vc, Wd, out, 0, NN);
  } else {
    for (int b=0; b<BATCH; b++) {
      score_kernel<<<dim3(32,32), 256, 0, stream>>>(Qh, Kh, S, b);
      select_kernel<<<1024, 256, 0, stream>>>(S, Wd);
      pv_gemm<<<dim3(2,64,1), 256, 0, stream>>>(Vc, Wd, out, b, 0);
    }
  }
}

// Round 10
// 321.433 us; speedup vs baseline: 1.7422x; 1.2437x over previous
//
#include <hip/hip_runtime.h>
#include <stdint.h>

#define BATCH 4
#define CH    256
#define NTOK  4096
#define KSEL  409          // int(0.1 * 4096)

typedef unsigned short u16;
typedef unsigned int   u32;
typedef unsigned long long u64;

typedef __attribute__((ext_vector_type(8))) _Float16 half8;
typedef __attribute__((ext_vector_type(4))) _Float16 half4;
typedef __attribute__((ext_vector_type(4))) float f32x4;
typedef __attribute__((ext_vector_type(4))) u32 u32x4;
typedef __attribute__((ext_vector_type(2))) u32 u32x2;
typedef __attribute__((ext_vector_type(4))) float fl4;

// ---------------- helpers ----------------
__device__ inline u16 h2u(_Float16 h){ u16 u; __builtin_memcpy(&u,&h,2); return u; }
__device__ inline float u2f16(u32 v){ _Float16 h; u16 uu=(u16)v; __builtin_memcpy(&h,&uu,2); return (float)h; }
// monotone 16-bit fp16<->uint key transform (ascending)
__device__ inline float kinv16(u32 k){
  u32 v = (k & 0x8000u) ? (k & 0x7FFFu) : ((~k) & 0xFFFFu);
  return u2f16(v);
}
__device__ inline void gload16(const void* g, void* l){
  __builtin_amdgcn_global_load_lds((const __attribute__((address_space(1))) u32*)g,
                                   (__attribute__((address_space(3))) u32*)l, 16, 0, 0);
}

// ---------------- phase -1: W split ----------------
__global__ __launch_bounds__(256) void wsplit_kernel(
    const float* __restrict__ Wq, const float* __restrict__ Wk,
    const float* __restrict__ Wv, u16* __restrict__ W3h, u16* __restrict__ W3l)
{
  const int p = blockIdx.y;
  const float* W = (p==0)? Wq : (p==1)? Wk : Wv;
  const int idx = (blockIdx.x*256 + threadIdx.x) * 4;
  fl4 v = *(const fl4*)(W + idx);
  u32x2 vh, vl;
  #pragma unroll
  for (int q=0;q<2;q++) {
    _Float16 h0=(_Float16)v[q*2], h1=(_Float16)v[q*2+1];
    _Float16 l0=(_Float16)(v[q*2]-(float)h0), l1=(_Float16)(v[q*2+1]-(float)h1);
    vh[q] = (u32)h2u(h0) | ((u32)h2u(h1)<<16);
    vl[q] = (u32)h2u(l0) | ((u32)h2u(l1)<<16);
  }
  *(u32x2*)(W3h + p*CH*CH + idx) = vh;
  *(u32x2*)(W3l + p*CH*CH + idx) = vl;
}

// ---------------- phase 0a: x transpose + split ----------------
__global__ __launch_bounds__(256) void xsplit_kernel(
    const float* __restrict__ x, u16* __restrict__ xTh, u16* __restrict__ xTl)
{
  __shared__ float lds[64][65];
  const int tid = threadIdx.x;
  const int n0 = blockIdx.x << 6;
  const int c0 = blockIdx.y << 6;
  const int b  = blockIdx.z;
  const float* xb = x + (size_t)b*CH*NTOK;

  #pragma unroll
  for (int i=0;i<16;i++) {
    int c_l = (tid>>6) + (i<<2);
    int n_l = tid & 63;
    lds[c_l][n_l] = xb[(size_t)(c0+c_l)*NTOK + n0 + n_l];
  }
  __syncthreads();
  u16* oh = xTh + (size_t)b*NTOK*CH;
  u16* ol = xTl + (size_t)b*NTOK*CH;
  #pragma unroll
  for (int i=0;i<16;i++) {
    int n_l = (tid>>6) + (i<<2);
    int c_l = tid & 63;
    float v = lds[c_l][n_l];
    _Float16 h = (_Float16)v;
    _Float16 l = (_Float16)(v - (float)h);
    size_t o = (size_t)(n0+n_l)*CH + c0 + c_l;
    oh[o] = h2u(h);
    ol[o] = h2u(l);
  }
}

// ---------------- phase 0b: QKV projection GEMM ----------------
__global__ __launch_bounds__(256) void proj_gemm(
    const u16* __restrict__ xTh, const u16* __restrict__ xTl,
    const u16* __restrict__ W3h, const u16* __restrict__ W3l,
    u16* __restrict__ Qh, u16* __restrict__ Kh, u16* __restrict__ Vc)
{
  __shared__ __align__(16) short lds[4*128*64];   // ah, al, bh, bl (16KB each)
  short* lds_ah = lds;
  short* lds_al = lds + 128*64;
  short* lds_bh = lds + 2*128*64;
  short* lds_bl = lds + 3*128*64;

  const int tid  = threadIdx.x;
  const int lane = tid & 63;
  const int wave = tid >> 6;
  const int wm = wave >> 1, wn = wave & 1;
  const int brow = blockIdx.x << 7;     // token tile
  const int bcol = blockIdx.y << 7;     // out-channel tile
  const int z = blockIdx.z;             // b*3 + p
  const int b = z / 3, p = z - 3*b;

  const u16* Agh = xTh + ((size_t)b*NTOK + brow)*CH;
  const u16* Agl = xTl + ((size_t)b*NTOK + brow)*CH;
  const u16* Bgh = W3h + (size_t)p*CH*CH + (size_t)bcol*CH;
  const u16* Bgl = W3l + (size_t)p*CH*CH + (size_t)bcol*CH;

  f32x4 acc[4][4];
  #pragma unroll
  for (int i=0;i<4;i++)
    #pragma unroll
    for (int j=0;j<4;j++) acc[i][j] = (f32x4)0.f;

  const int sr    = tid >> 3;
  const int sslot = tid & 7;

  for (int kt=0; kt<4; kt++) {
    #pragma unroll
    for (int c=0;c<4;c++) {
      int r  = (c<<5) + sr;
      int ss = sslot ^ (r & 7);
      size_t goff = (size_t)r*CH + (kt<<6) + (ss<<3);
      int dst = (c<<12) + (wave<<10);
      gload16(Agh + goff, (char*)lds_ah + dst);
      gload16(Agl + goff, (char*)lds_al + dst);
      gload16(Bgh + goff, (char*)lds_bh + dst);
      gload16(Bgl + goff, (char*)lds_bl + dst);
    }
    __syncthreads();
    #pragma unroll
    for (int ks=0;ks<2;ks++) {
      half8 ah[4], al[4], bh[4], bl[4];
      const int kg = lane >> 4;
      const int rl = lane & 15;
      #pragma unroll
      for (int t=0;t<4;t++) {
        int ar = (wm<<6) + (t<<4) + rl;
        int slot = (ks<<2) + kg;
        int ao = ar*64 + ((slot ^ (ar&7))<<3);
        ah[t] = *(const half8*)&lds_ah[ao];
        al[t] = *(const half8*)&lds_al[ao];
        int br = (wn<<6) + (t<<4) + rl;
        int bo = br*64 + ((slot ^ (br&7))<<3);
        bh[t] = *(const half8*)&lds_bh[bo];
        bl[t] = *(const half8*)&lds_bl[bo];
      }
      #pragma unroll
      for (int mt=0;mt<4;mt++)
        #pragma unroll
        for (int nt=0;nt<4;nt++) {
          acc[mt][nt] = __builtin_amdgcn_mfma_f32_16x16x32_f16(ah[mt], bh[nt], acc[mt][nt], 0,0,0);
          acc[mt][nt] = __builtin_amdgcn_mfma_f32_16x16x32_f16(ah[mt], bl[nt], acc[mt][nt], 0,0,0);
          acc[mt][nt] = __builtin_amdgcn_mfma_f32_16x16x32_f16(al[mt], bh[nt], acc[mt][nt], 0,0,0);
        }
    }
    __syncthreads();
  }

  const int rl = lane & 15, rg = lane >> 4;
  if (p < 2) {
    u16* oh = ((p==0)? Qh : Kh) + (size_t)b*NTOK*CH;
    #pragma unroll
    for (int mt=0;mt<4;mt++) {
      #pragma unroll
      for (int nt=0;nt<4;nt++) {
        int n = brow + (wm<<6) + (mt<<4) + (rg<<2);
        int c = bcol + (wn<<6) + (nt<<4) + rl;
        #pragma unroll
        for (int r=0;r<4;r++)
          oh[(size_t)(n+r)*CH + c] = h2u((_Float16)acc[mt][nt][r]);
      }
    }
  } else {
    // V: transpose in LDS -> store channel-major Vc[b][d][n] coalesced
    u16* ldsT = (u16*)lds;                 // [128][136] u16
    #pragma unroll
    for (int mt=0;mt<4;mt++) {
      #pragma unroll
      for (int nt=0;nt<4;nt++) {
        int n_l = (wm<<6) + (mt<<4) + (rg<<2);
        int c_l = (wn<<6) + (nt<<4) + rl;
        half4 hv;
        #pragma unroll
        for (int r=0;r<4;r++) hv[r] = (_Float16)acc[mt][nt][r];
        *(half4*)&ldsT[c_l*136 + n_l] = hv;
      }
    }
    __syncthreads();
    u16* ov = Vc + (size_t)b*CH*NTOK + (size_t)bcol*NTOK + brow;
    #pragma unroll
    for (int i=0;i<32;i++) {
      int d_l = (tid>>6) + (i<<2);
      u32 v = *(const u32*)&ldsT[d_l*136 + (lane<<1)];
      *(u32*)(ov + (size_t)d_l*NTOK + (lane<<1)) = v;
    }
  }
}

// ---------------- phase 1: S = Q*K^T / 16 (one batch), hi-only fp16, fp16 output ----------------
__global__ __launch_bounds__(256) void score_kernel(
    const u16* __restrict__ Qh, const u16* __restrict__ Kh,
    u16* __restrict__ S, int b)
{
  __shared__ __align__(16) short lds_a[128*64];
  __shared__ __align__(16) short lds_b[128*64];
  const int tid  = threadIdx.x;
  const int lane = tid & 63;
  const int wave = tid >> 6;
  const int wm = wave >> 1, wn = wave & 1;
  const int brow = blockIdx.x << 7, bcol = blockIdx.y << 7;

  const u16* Ag = Qh + ((size_t)b*NTOK + brow)*CH;
  const u16* Bg = Kh + ((size_t)b*NTOK + bcol)*CH;

  f32x4 acc[4][4];
  #pragma unroll
  for (int i=0;i<4;i++)
    #pragma unroll
    for (int j=0;j<4;j++) acc[i][j] = (f32x4)0.f;

  const int sr    = tid >> 3;
  const int sslot = tid & 7;

  for (int kt=0; kt<4; kt++) {
    #pragma unroll
    for (int c=0;c<4;c++) {
      int r  = (c<<5) + sr;
      int ss = sslot ^ (r & 7);
      size_t goff = (size_t)r*CH + (kt<<6) + (ss<<3);
      int dst = (c<<12) + (wave<<10);
      gload16(Ag + goff, (char*)lds_a + dst);
      gload16(Bg + goff, (char*)lds_b + dst);
    }
    __syncthreads();
    #pragma unroll
    for (int ks=0;ks<2;ks++) {
      half8 af[4], bf[4];
      const int kg = lane >> 4;
      const int rl = lane & 15;
      #pragma unroll
      for (int t=0;t<4;t++) {
        int ar = (wm<<6) + (t<<4) + rl;
        int slot = (ks<<2) + kg;
        af[t] = *(const half8*)&lds_a[ar*64 + ((slot ^ (ar&7))<<3)];
        int br = (wn<<6) + (t<<4) + rl;
        bf[t] = *(const half8*)&lds_b[br*64 + ((slot ^ (br&7))<<3)];
      }
      #pragma unroll
      for (int mt=0;mt<4;mt++)
        #pragma unroll
        for (int nt=0;nt<4;nt++)
          acc[mt][nt] = __builtin_amdgcn_mfma_f32_16x16x32_f16(af[mt], bf[nt], acc[mt][nt], 0,0,0);
    }
    __syncthreads();
  }

  const int rl = lane & 15, rg = lane >> 4;
  #pragma unroll
  for (int mt=0;mt<4;mt++) {
    #pragma unroll
    for (int nt=0;nt<4;nt++) {
      int row = brow + (wm<<6) + (mt<<4) + (rg<<2);
      int col = bcol + (wn<<6) + (nt<<4) + rl;
      #pragma unroll
      for (int r=0;r<4;r++)
        S[(size_t)(row+r)*NTOK + col] = h2u((_Float16)(acc[mt][nt][r] * 0.0625f));
    }
  }
}

// ---------------- phase 2: exact per-row top-KSEL on fp16 scores ----------------
// one wave per row; 64 16-bit keys/lane (element = lane*64+ch -> 16B vector loads/stores).
// Exactly 2 radix-8 histogram passes exhaust the 16-bit key space: tkey exact, no fallback.
// Tie handling: all-included fast path; else ballot-ordered inclusion (any tie order is a
// <=1-ulp boundary swap vs the fp32 reference -- same error class as fp16 score rounding).
__global__ __launch_bounds__(256) void select_kernel(
    const u16* __restrict__ Sh, u16* __restrict__ Wd)
{
  __shared__ __align__(16) u32 hist[4][256];
  const int lane = threadIdx.x & 63;
  const int wave = threadIdx.x >> 6;
  const int row  = (blockIdx.x << 2) + wave;
  const u16* Srow = Sh + (size_t)row * NTOK + (lane << 6);

  u32 key[64];
  u32 umax = 0;
  #pragma unroll
  for (int g=0; g<8; ++g) {
    u32x4 q = *(const u32x4*)(Srow + (g<<3));
    #pragma unroll
    for (int j=0; j<4; ++j) {
      u32 w = q[j];
      u32 a = w & 0xFFFFu, bb = w >> 16;
      a  = (a  & 0x8000u) ? ((~a)  & 0xFFFFu) : (a  | 0x8000u);
      bb = (bb & 0x8000u) ? ((~bb) & 0xFFFFu) : (bb | 0x8000u);
      key[(g<<3)+(j<<1)  ] = a;
      key[(g<<3)+(j<<1)+1] = bb;
      umax = umax > a  ? umax : a;
      umax = umax > bb ? umax : bb;
    }
  }
  #pragma unroll
  for (int off=32; off; off>>=1) { u32 o = __shfl_xor(umax, off, 64); umax = o>umax ? o : umax; }
  const float m = kinv16(umax);

  u32 krem = KSEL, prefix = 0, cb = 0;
  #pragma unroll
  for (int pass=0; pass<2; ++pass) {
    const int shift = 8 - (pass<<3);           // 8 then 0
    #pragma unroll
    for (int i=0;i<4;i++) hist[wave][(i<<6)+lane] = 0u;
    __asm__ volatile("s_waitcnt lgkmcnt(0)" ::: "memory");
    if (pass == 0) {
      #pragma unroll
      for (int ch=0; ch<64; ch++) atomicAdd(&hist[wave][key[ch] >> 8], 1u);
    } else {
      const u32 b1 = prefix >> 8;
      #pragma unroll
      for (int ch=0; ch<64; ch++)
        if ((key[ch] >> 8) == b1) atomicAdd(&hist[wave][key[ch] & 255u], 1u);
    }
    __asm__ volatile("s_waitcnt lgkmcnt(0)" ::: "memory");
    u32x4 h = *(const u32x4*)&hist[wave][lane<<2];
    u32 tot = h[0]+h[1]+h[2]+h[3];
    u32 sfx = tot;
    #pragma unroll
    for (int off=1; off<64; off<<=1) {
      u32 v = __shfl_down(sfx, off, 64);
      if (lane + off < 64) sfx += v;
    }
    u32 s3 = (sfx - tot) + h[3];
    u32 s2 = s3 + h[2];
    u32 s1 = s2 + h[1];
    u32 s0 = s1 + h[0];
    u32 s4 = s3 - h[3];
    u32 kr = krem;
    u32 enc = 0;
    if (s0 >= kr && s1 < kr) enc = ((u32)((lane<<2)+0)<<22) | (h[0]<<9) | (kr - s1);
    if (s1 >= kr && s2 < kr) enc = ((u32)((lane<<2)+1)<<22) | (h[1]<<9) | (kr - s2);
    if (s2 >= kr && s3 < kr) enc = ((u32)((lane<<2)+2)<<22) | (h[2]<<9) | (kr - s3);
    if (s3 >= kr && s4 < kr) enc = ((u32)((lane<<2)+3)<<22) | (h[3]<<9) | (kr - s4);
    #pragma unroll
    for (int off=32; off; off>>=1) { u32 o = __shfl_xor(enc, off, 64); enc = (o>enc)? o:enc; }
    prefix |= (enc >> 22) << shift;
    cb      = (enc >> 9) & 0x1FFFu;
    krem    = enc & 0x1FFu;
  }
  const u32 tkey = prefix;                    // exact KSEL-th-largest fp16 key

  // selection bitmask
  u64 selb = 0;
  if (cb == krem) {
    #pragma unroll
    for (int ch=0; ch<64; ch++)
      if (key[ch] >= tkey) selb |= (1ull << ch);
  } else {
    const u64 ltmask = (1ull << lane) - 1ull;
    int eqbase = 0;
    #pragma unroll
    for (int ch=0; ch<64; ch++) {
      bool eq = (key[ch] == tkey);
      u64 eqm = __ballot(eq);
      bool sel = (key[ch] > tkey) || (eq && (eqbase + __popcll(eqm & ltmask)) < (int)krem);
      if (sel) selb |= (1ull << ch);
      eqbase += __popcll(eqm);
    }
  }

  // exp + denominator (cache e in key regs)
  float z = 0.f;
  #pragma unroll
  for (int ch=0; ch<64; ch++) {
    float e = __expf(kinv16(key[ch]) - m);
    if ((selb >> ch) & 1ull) z += e;
    key[ch] = __float_as_uint(e);
  }
  #pragma unroll
  for (int off=32; off; off>>=1) z += __shfl_xor(z, off, 64);
  const float invZ = 1.f / z;

  // vectorized dense weight row write (element = lane*64+ch)
  u16* wp = Wd + (size_t)row * NTOK + (lane << 6);
  #pragma unroll
  for (int g=0; g<8; ++g) {
    u32x4 v;
    #pragma unroll
    for (int j=0; j<4; ++j) {
      int i0 = (g<<3)+(j<<1), i1 = i0+1;
      float w0 = ((selb >> i0) & 1ull) ? __uint_as_float(key[i0]) * invZ : 0.f;
      float w1 = ((selb >> i1) & 1ull) ? __uint_as_float(key[i1]) * invZ : 0.f;
      v[j] = (u32)h2u((_Float16)w0) | ((u32)h2u((_Float16)w1) << 16);
    }
    *(u32x4*)(wp + (g<<3)) = v;
  }
}

// ---------------- phase 3: dense PV GEMM, 2-phase double-buffered staging ----------------
// out^T[c,n] = sum_k Vc[c,k] * Wd[n,k].  128(M=ch) x 64(N=tok) tiles, K=NTOK, BK=64.
// STAGE(next) issued BEFORE compute(cur); single barrier per iteration drains after compute.
__global__ __launch_bounds__(256) void pv_gemm(
    const u16* __restrict__ Vc, const u16* __restrict__ Wd,
    float* __restrict__ out, int b_base, size_t wstride)
{
  __shared__ __align__(16) short lds_a[2][128*64];   // 32 KB
  __shared__ __align__(16) short lds_b[2][64*64];    // 16 KB
  const int tid  = threadIdx.x;
  const int lane = tid & 63;
  const int wave = tid >> 6;
  const int wm = wave >> 1, wn = wave & 1;
  const int b    = b_base + blockIdx.z;
  const int brow = blockIdx.x << 7;      // channel tile (0/128)
  const int bcol = blockIdx.y << 6;      // token tile (64-wide)

  const u16* Ag = Vc + (size_t)b*CH*NTOK + (size_t)brow*NTOK;
  const u16* Bg = Wd + (size_t)blockIdx.z*wstride + (size_t)bcol*NTOK;

  f32x4 acc[4][2];
  #pragma unroll
  for (int i=0;i<4;i++)
    #pragma unroll
    for (int j=0;j<2;j++) acc[i][j] = (f32x4)0.f;

  const int sr    = tid >> 3;
  const int sslot = tid & 7;

  auto STAGE = [&](int buf, int kt) {
    #pragma unroll
    for (int c=0;c<4;c++) {
      int r  = (c<<5) + sr;
      int ss = sslot ^ (r & 7);
      gload16(Ag + (size_t)r*NTOK + (kt<<6) + (ss<<3),
              (char*)lds_a[buf] + (c<<12) + (wave<<10));
    }
    #pragma unroll
    for (int c=0;c<2;c++) {
      int r  = (c<<5) + sr;
      int ss = sslot ^ (r & 7);
      gload16(Bg + (size_t)r*NTOK + (kt<<6) + (ss<<3),
              (char*)lds_b[buf] + (c<<12) + (wave<<10));
    }
  };

  STAGE(0, 0);
  __syncthreads();
  int cur = 0;
  for (int kt=0; kt<64; ++kt) {
    if (kt < 63) STAGE(cur^1, kt+1);     // next-tile loads in flight during compute
    const short* la = lds_a[cur];
    const short* lb = lds_b[cur];
    #pragma unroll
    for (int ks=0;ks<2;ks++) {
      half8 af[4], bf[2];
      const int kg = lane >> 4;
      const int rl = lane & 15;
      const int slot = (ks<<2) + kg;
      #pragma unroll
      for (int t=0;t<4;t++) {
        int ar = (wm<<6) + (t<<4) + rl;
        af[t] = *(const half8*)&la[ar*64 + ((slot ^ (ar&7))<<3)];
      }
      #pragma unroll
      for (int t=0;t<2;t++) {
        int br = (wn<<5) + (t<<4) + rl;
        bf[t] = *(const half8*)&lb[br*64 + ((slot ^ (br&7))<<3)];
      }
      #pragma unroll
      for (int mt=0;mt<4;mt++)
        #pragma unroll
        for (int nt=0;nt<2;nt++)
          acc[mt][nt] = __builtin_amdgcn_mfma_f32_16x16x32_f16(af[mt], bf[nt], acc[mt][nt], 0,0,0);
    }
    __syncthreads();                     // drains next-tile loads (had full compute to land)
    cur ^= 1;
  }

  float* ob = out + (size_t)b*CH*NTOK;
  const int rl = lane & 15, rg = lane >> 4;
  #pragma unroll
  for (int mt=0;mt<4;mt++) {
    #pragma unroll
    for (int nt=0;nt<2;nt++) {
      int row = brow + (wm<<6) + (mt<<4) + (rg<<2);   // channel
      int col = bcol + (wn<<5) + (nt<<4) + rl;        // token
      #pragma unroll
      for (int r=0;r<4;r++)
        ob[(size_t)(row+r)*NTOK + col] = acc[mt][nt][r];
    }
  }
}

// ---------------- launcher ----------------
extern "C" void kernel_launch(void* const* d_in, const int* in_sizes, int n_in,
                              void* d_out, int out_size, void* d_ws, size_t ws_size,
                              hipStream_t stream)
{
  (void)in_sizes; (void)n_in; (void)out_size;
  const float* x  = (const float*)d_in[0];
  const float* Wq = (const float*)d_in[1];
  const float* Wk = (const float*)d_in[2];
  const float* Wv = (const float*)d_in[3];
  float* out = (float*)d_out;

  char* ws = (char*)d_ws;
  size_t off = 0;
  const size_t plane = (size_t)BATCH*NTOK*CH*2;       // 8.4 MB fp16 plane
  const size_t NN    = (size_t)NTOK*NTOK;             // 16.8M elements
  u16* Qh = (u16*)(ws + off); off += plane;
  u16* Kh = (u16*)(ws + off); off += plane;
  u16* Vc = (u16*)(ws + off); off += plane;
  u16* W3h = (u16*)(ws + off); off += (size_t)3*CH*CH*2;
  u16* W3l = (u16*)(ws + off); off += (size_t)3*CH*CH*2;
  // xT planes live only until proj_gemm completes; Wd/S overlap them afterwards.
  const size_t xt_base = off;
  u16* xTh = (u16*)(ws + xt_base);
  u16* xTl = (u16*)(ws + xt_base + plane);
  const size_t fullW_need = xt_base + (size_t)BATCH*NN*2 + NN*2;   // ~194 MiB
  const bool fullW = ws_size >= fullW_need;
  u16* Wd = (u16*)(ws + xt_base);
  u16* S  = (u16*)(ws + xt_base + (fullW ? (size_t)BATCH*NN*2 : NN*2));

  wsplit_kernel<<<dim3(64,3), 256, 0, stream>>>(Wq, Wk, Wv, W3h, W3l);
  xsplit_kernel<<<dim3(64,4,4), 256, 0, stream>>>(x, xTh, xTl);
  proj_gemm<<<dim3(32,2,12), 256, 0, stream>>>(xTh, xTl, W3h, W3l, Qh, Kh, Vc);

  if (fullW) {
    for (int b=0; b<BATCH; b++) {
      score_kernel<<<dim3(32,32), 256, 0, stream>>>(Qh, Kh, S, b);
      select_kernel<<<1024, 256, 0, stream>>>(S, Wd + (size_t)b*NN);
    }
    pv_gemm<<<dim3(2,64,4), 256, 0, stream>>>(Vc, Wd, out, 0, NN);
  } else {
    for (int b=0; b<BATCH; b++) {
      score_kernel<<<dim3(32,32), 256, 0, stream>>>(Qh, Kh, S, b);
      select_kernel<<<1024, 256, 0, stream>>>(S, Wd);
      pv_gemm<<<dim3(2,64,1), 256, 0, stream>>>(Vc, Wd, out, b, 0);
    }
  }
}

// Round 11
// 300.741 us; speedup vs baseline: 1.8621x; 1.0688x over previous
//
#include <hip/hip_runtime.h>
#include <stdint.h>

#define BATCH 4
#define CH    256
#define NTOK  4096
#define KSEL  409          // int(0.1 * 4096)

typedef unsigned short u16;
typedef unsigned int   u32;
typedef unsigned long long u64;

typedef __attribute__((ext_vector_type(8))) _Float16 half8;
typedef __attribute__((ext_vector_type(4))) _Float16 half4;
typedef __attribute__((ext_vector_type(4))) float f32x4;
typedef __attribute__((ext_vector_type(4))) u32 u32x4;
typedef __attribute__((ext_vector_type(2))) u32 u32x2;
typedef __attribute__((ext_vector_type(4))) float fl4;

// ---------------- helpers ----------------
__device__ inline u16 h2u(_Float16 h){ u16 u; __builtin_memcpy(&u,&h,2); return u; }
__device__ inline float u2f16(u32 v){ _Float16 h; u16 uu=(u16)v; __builtin_memcpy(&h,&uu,2); return (float)h; }
// monotone 16-bit fp16<->uint key transform (ascending)
__device__ inline float kinv16(u32 k){
  u32 v = (k & 0x8000u) ? (k & 0x7FFFu) : ((~k) & 0xFFFFu);
  return u2f16(v);
}
__device__ inline void gload16(const void* g, void* l){
  __builtin_amdgcn_global_load_lds((const __attribute__((address_space(1))) u32*)g,
                                   (__attribute__((address_space(3))) u32*)l, 16, 0, 0);
}

// ---------------- phase -1: W split ----------------
__global__ __launch_bounds__(256) void wsplit_kernel(
    const float* __restrict__ Wq, const float* __restrict__ Wk,
    const float* __restrict__ Wv, u16* __restrict__ W3h, u16* __restrict__ W3l)
{
  const int p = blockIdx.y;
  const float* W = (p==0)? Wq : (p==1)? Wk : Wv;
  const int idx = (blockIdx.x*256 + threadIdx.x) * 4;
  fl4 v = *(const fl4*)(W + idx);
  u32x2 vh, vl;
  #pragma unroll
  for (int q=0;q<2;q++) {
    _Float16 h0=(_Float16)v[q*2], h1=(_Float16)v[q*2+1];
    _Float16 l0=(_Float16)(v[q*2]-(float)h0), l1=(_Float16)(v[q*2+1]-(float)h1);
    vh[q] = (u32)h2u(h0) | ((u32)h2u(h1)<<16);
    vl[q] = (u32)h2u(l0) | ((u32)h2u(l1)<<16);
  }
  *(u32x2*)(W3h + p*CH*CH + idx) = vh;
  *(u32x2*)(W3l + p*CH*CH + idx) = vl;
}

// ---------------- phase 0a: x transpose + split ----------------
__global__ __launch_bounds__(256) void xsplit_kernel(
    const float* __restrict__ x, u16* __restrict__ xTh, u16* __restrict__ xTl)
{
  __shared__ float lds[64][65];
  const int tid = threadIdx.x;
  const int n0 = blockIdx.x << 6;
  const int c0 = blockIdx.y << 6;
  const int b  = blockIdx.z;
  const float* xb = x + (size_t)b*CH*NTOK;

  #pragma unroll
  for (int i=0;i<16;i++) {
    int c_l = (tid>>6) + (i<<2);
    int n_l = tid & 63;
    lds[c_l][n_l] = xb[(size_t)(c0+c_l)*NTOK + n0 + n_l];
  }
  __syncthreads();
  u16* oh = xTh + (size_t)b*NTOK*CH;
  u16* ol = xTl + (size_t)b*NTOK*CH;
  #pragma unroll
  for (int i=0;i<16;i++) {
    int n_l = (tid>>6) + (i<<2);
    int c_l = tid & 63;
    float v = lds[c_l][n_l];
    _Float16 h = (_Float16)v;
    _Float16 l = (_Float16)(v - (float)h);
    size_t o = (size_t)(n0+n_l)*CH + c0 + c_l;
    oh[o] = h2u(h);
    ol[o] = h2u(l);
  }
}

// ---------------- phase 0b: QKV projection GEMM ----------------
__global__ __launch_bounds__(256) void proj_gemm(
    const u16* __restrict__ xTh, const u16* __restrict__ xTl,
    const u16* __restrict__ W3h, const u16* __restrict__ W3l,
    u16* __restrict__ Qh, u16* __restrict__ Kh, u16* __restrict__ Vc)
{
  __shared__ __align__(16) short lds[4*128*64];   // ah, al, bh, bl (16KB each)
  short* lds_ah = lds;
  short* lds_al = lds + 128*64;
  short* lds_bh = lds + 2*128*64;
  short* lds_bl = lds + 3*128*64;

  const int tid  = threadIdx.x;
  const int lane = tid & 63;
  const int wave = tid >> 6;
  const int wm = wave >> 1, wn = wave & 1;
  const int brow = blockIdx.x << 7;     // token tile
  const int bcol = blockIdx.y << 7;     // out-channel tile
  const int z = blockIdx.z;             // b*3 + p
  const int b = z / 3, p = z - 3*b;

  const u16* Agh = xTh + ((size_t)b*NTOK + brow)*CH;
  const u16* Agl = xTl + ((size_t)b*NTOK + brow)*CH;
  const u16* Bgh = W3h + (size_t)p*CH*CH + (size_t)bcol*CH;
  const u16* Bgl = W3l + (size_t)p*CH*CH + (size_t)bcol*CH;

  f32x4 acc[4][4];
  #pragma unroll
  for (int i=0;i<4;i++)
    #pragma unroll
    for (int j=0;j<4;j++) acc[i][j] = (f32x4)0.f;

  const int sr    = tid >> 3;
  const int sslot = tid & 7;

  for (int kt=0; kt<4; kt++) {
    #pragma unroll
    for (int c=0;c<4;c++) {
      int r  = (c<<5) + sr;
      int ss = sslot ^ (r & 7);
      size_t goff = (size_t)r*CH + (kt<<6) + (ss<<3);
      int dst = (c<<12) + (wave<<10);
      gload16(Agh + goff, (char*)lds_ah + dst);
      gload16(Agl + goff, (char*)lds_al + dst);
      gload16(Bgh + goff, (char*)lds_bh + dst);
      gload16(Bgl + goff, (char*)lds_bl + dst);
    }
    __syncthreads();
    #pragma unroll
    for (int ks=0;ks<2;ks++) {
      half8 ah[4], al[4], bh[4], bl[4];
      const int kg = lane >> 4;
      const int rl = lane & 15;
      #pragma unroll
      for (int t=0;t<4;t++) {
        int ar = (wm<<6) + (t<<4) + rl;
        int slot = (ks<<2) + kg;
        int ao = ar*64 + ((slot ^ (ar&7))<<3);
        ah[t] = *(const half8*)&lds_ah[ao];
        al[t] = *(const half8*)&lds_al[ao];
        int br = (wn<<6) + (t<<4) + rl;
        int bo = br*64 + ((slot ^ (br&7))<<3);
        bh[t] = *(const half8*)&lds_bh[bo];
        bl[t] = *(const half8*)&lds_bl[bo];
      }
      #pragma unroll
      for (int mt=0;mt<4;mt++)
        #pragma unroll
        for (int nt=0;nt<4;nt++) {
          acc[mt][nt] = __builtin_amdgcn_mfma_f32_16x16x32_f16(ah[mt], bh[nt], acc[mt][nt], 0,0,0);
          acc[mt][nt] = __builtin_amdgcn_mfma_f32_16x16x32_f16(ah[mt], bl[nt], acc[mt][nt], 0,0,0);
          acc[mt][nt] = __builtin_amdgcn_mfma_f32_16x16x32_f16(al[mt], bh[nt], acc[mt][nt], 0,0,0);
        }
    }
    __syncthreads();
  }

  const int rl = lane & 15, rg = lane >> 4;
  if (p < 2) {
    u16* oh = ((p==0)? Qh : Kh) + (size_t)b*NTOK*CH;
    #pragma unroll
    for (int mt=0;mt<4;mt++) {
      #pragma unroll
      for (int nt=0;nt<4;nt++) {
        int n = brow + (wm<<6) + (mt<<4) + (rg<<2);
        int c = bcol + (wn<<6) + (nt<<4) + rl;
        #pragma unroll
        for (int r=0;r<4;r++)
          oh[(size_t)(n+r)*CH + c] = h2u((_Float16)acc[mt][nt][r]);
      }
    }
  } else {
    // V: transpose in LDS -> store channel-major Vc[b][d][n] coalesced
    u16* ldsT = (u16*)lds;                 // [128][136] u16
    #pragma unroll
    for (int mt=0;mt<4;mt++) {
      #pragma unroll
      for (int nt=0;nt<4;nt++) {
        int n_l = (wm<<6) + (mt<<4) + (rg<<2);
        int c_l = (wn<<6) + (nt<<4) + rl;
        half4 hv;
        #pragma unroll
        for (int r=0;r<4;r++) hv[r] = (_Float16)acc[mt][nt][r];
        *(half4*)&ldsT[c_l*136 + n_l] = hv;
      }
    }
    __syncthreads();
    u16* ov = Vc + (size_t)b*CH*NTOK + (size_t)bcol*NTOK + brow;
    #pragma unroll
    for (int i=0;i<32;i++) {
      int d_l = (tid>>6) + (i<<2);
      u32 v = *(const u32*)&ldsT[d_l*136 + (lane<<1)];
      *(u32*)(ov + (size_t)d_l*NTOK + (lane<<1)) = v;
    }
  }
}

// ---------------- phase 1: S = Q*K^T / 16 (one batch), hi-only fp16, fp16 output ----------------
__global__ __launch_bounds__(256) void score_kernel(
    const u16* __restrict__ Qh, const u16* __restrict__ Kh,
    u16* __restrict__ S, int b)
{
  __shared__ __align__(16) short lds_a[128*64];
  __shared__ __align__(16) short lds_b[128*64];
  const int tid  = threadIdx.x;
  const int lane = tid & 63;
  const int wave = tid >> 6;
  const int wm = wave >> 1, wn = wave & 1;
  const int brow = blockIdx.x << 7, bcol = blockIdx.y << 7;

  const u16* Ag = Qh + ((size_t)b*NTOK + brow)*CH;
  const u16* Bg = Kh + ((size_t)b*NTOK + bcol)*CH;

  f32x4 acc[4][4];
  #pragma unroll
  for (int i=0;i<4;i++)
    #pragma unroll
    for (int j=0;j<4;j++) acc[i][j] = (f32x4)0.f;

  const int sr    = tid >> 3;
  const int sslot = tid & 7;

  for (int kt=0; kt<4; kt++) {
    #pragma unroll
    for (int c=0;c<4;c++) {
      int r  = (c<<5) + sr;
      int ss = sslot ^ (r & 7);
      size_t goff = (size_t)r*CH + (kt<<6) + (ss<<3);
      int dst = (c<<12) + (wave<<10);
      gload16(Ag + goff, (char*)lds_a + dst);
      gload16(Bg + goff, (char*)lds_b + dst);
    }
    __syncthreads();
    #pragma unroll
    for (int ks=0;ks<2;ks++) {
      half8 af[4], bf[4];
      const int kg = lane >> 4;
      const int rl = lane & 15;
      #pragma unroll
      for (int t=0;t<4;t++) {
        int ar = (wm<<6) + (t<<4) + rl;
        int slot = (ks<<2) + kg;
        af[t] = *(const half8*)&lds_a[ar*64 + ((slot ^ (ar&7))<<3)];
        int br = (wn<<6) + (t<<4) + rl;
        bf[t] = *(const half8*)&lds_b[br*64 + ((slot ^ (br&7))<<3)];
      }
      #pragma unroll
      for (int mt=0;mt<4;mt++)
        #pragma unroll
        for (int nt=0;nt<4;nt++)
          acc[mt][nt] = __builtin_amdgcn_mfma_f32_16x16x32_f16(af[mt], bf[nt], acc[mt][nt], 0,0,0);
    }
    __syncthreads();
  }

  const int rl = lane & 15, rg = lane >> 4;
  #pragma unroll
  for (int mt=0;mt<4;mt++) {
    #pragma unroll
    for (int nt=0;nt<4;nt++) {
      int row = brow + (wm<<6) + (mt<<4) + (rg<<2);
      int col = bcol + (wn<<6) + (nt<<4) + rl;
      #pragma unroll
      for (int r=0;r<4;r++)
        S[(size_t)(row+r)*NTOK + col] = h2u((_Float16)(acc[mt][nt][r] * 0.0625f));
    }
  }
}

// ---------------- phase 2: exact per-row top-KSEL on fp16 scores ----------------
__global__ __launch_bounds__(256) void select_kernel(
    const u16* __restrict__ Sh, u16* __restrict__ Wd)
{
  __shared__ __align__(16) u32 hist[4][256];
  const int lane = threadIdx.x & 63;
  const int wave = threadIdx.x >> 6;
  const int row  = (blockIdx.x << 2) + wave;
  const u16* Srow = Sh + (size_t)row * NTOK + (lane << 6);

  u32 key[64];
  u32 umax = 0;
  #pragma unroll
  for (int g=0; g<8; ++g) {
    u32x4 q = *(const u32x4*)(Srow + (g<<3));
    #pragma unroll
    for (int j=0; j<4; ++j) {
      u32 w = q[j];
      u32 a = w & 0xFFFFu, bb = w >> 16;
      a  = (a  & 0x8000u) ? ((~a)  & 0xFFFFu) : (a  | 0x8000u);
      bb = (bb & 0x8000u) ? ((~bb) & 0xFFFFu) : (bb | 0x8000u);
      key[(g<<3)+(j<<1)  ] = a;
      key[(g<<3)+(j<<1)+1] = bb;
      umax = umax > a  ? umax : a;
      umax = umax > bb ? umax : bb;
    }
  }
  #pragma unroll
  for (int off=32; off; off>>=1) { u32 o = __shfl_xor(umax, off, 64); umax = o>umax ? o : umax; }
  const float m = kinv16(umax);

  u32 krem = KSEL, prefix = 0, cb = 0;
  #pragma unroll
  for (int pass=0; pass<2; ++pass) {
    const int shift = 8 - (pass<<3);           // 8 then 0
    #pragma unroll
    for (int i=0;i<4;i++) hist[wave][(i<<6)+lane] = 0u;
    __asm__ volatile("s_waitcnt lgkmcnt(0)" ::: "memory");
    if (pass == 0) {
      #pragma unroll
      for (int ch=0; ch<64; ch++) atomicAdd(&hist[wave][key[ch] >> 8], 1u);
    } else {
      const u32 b1 = prefix >> 8;
      #pragma unroll
      for (int ch=0; ch<64; ch++)
        if ((key[ch] >> 8) == b1) atomicAdd(&hist[wave][key[ch] & 255u], 1u);
    }
    __asm__ volatile("s_waitcnt lgkmcnt(0)" ::: "memory");
    u32x4 h = *(const u32x4*)&hist[wave][lane<<2];
    u32 tot = h[0]+h[1]+h[2]+h[3];
    u32 sfx = tot;
    #pragma unroll
    for (int off=1; off<64; off<<=1) {
      u32 v = __shfl_down(sfx, off, 64);
      if (lane + off < 64) sfx += v;
    }
    u32 s3 = (sfx - tot) + h[3];
    u32 s2 = s3 + h[2];
    u32 s1 = s2 + h[1];
    u32 s0 = s1 + h[0];
    u32 s4 = s3 - h[3];
    u32 kr = krem;
    u32 enc = 0;
    if (s0 >= kr && s1 < kr) enc = ((u32)((lane<<2)+0)<<22) | (h[0]<<9) | (kr - s1);
    if (s1 >= kr && s2 < kr) enc = ((u32)((lane<<2)+1)<<22) | (h[1]<<9) | (kr - s2);
    if (s2 >= kr && s3 < kr) enc = ((u32)((lane<<2)+2)<<22) | (h[2]<<9) | (kr - s3);
    if (s3 >= kr && s4 < kr) enc = ((u32)((lane<<2)+3)<<22) | (h[3]<<9) | (kr - s4);
    #pragma unroll
    for (int off=32; off; off>>=1) { u32 o = __shfl_xor(enc, off, 64); enc = (o>enc)? o:enc; }
    prefix |= (enc >> 22) << shift;
    cb      = (enc >> 9) & 0x1FFFu;
    krem    = enc & 0x1FFu;
  }
  const u32 tkey = prefix;                    // exact KSEL-th-largest fp16 key

  // selection bitmask
  u64 selb = 0;
  if (cb == krem) {
    #pragma unroll
    for (int ch=0; ch<64; ch++)
      if (key[ch] >= tkey) selb |= (1ull << ch);
  } else {
    const u64 ltmask = (1ull << lane) - 1ull;
    int eqbase = 0;
    #pragma unroll
    for (int ch=0; ch<64; ch++) {
      bool eq = (key[ch] == tkey);
      u64 eqm = __ballot(eq);
      bool sel = (key[ch] > tkey) || (eq && (eqbase + __popcll(eqm & ltmask)) < (int)krem);
      if (sel) selb |= (1ull << ch);
      eqbase += __popcll(eqm);
    }
  }

  // exp + denominator (cache e in key regs)
  float z = 0.f;
  #pragma unroll
  for (int ch=0; ch<64; ch++) {
    float e = __expf(kinv16(key[ch]) - m);
    if ((selb >> ch) & 1ull) z += e;
    key[ch] = __float_as_uint(e);
  }
  #pragma unroll
  for (int off=32; off; off>>=1) z += __shfl_xor(z, off, 64);
  const float invZ = 1.f / z;

  // vectorized dense weight row write (element = lane*64+ch)
  u16* wp = Wd + (size_t)row * NTOK + (lane << 6);
  #pragma unroll
  for (int g=0; g<8; ++g) {
    u32x4 v;
    #pragma unroll
    for (int j=0; j<4; ++j) {
      int i0 = (g<<3)+(j<<1), i1 = i0+1;
      float w0 = ((selb >> i0) & 1ull) ? __uint_as_float(key[i0]) * invZ : 0.f;
      float w1 = ((selb >> i1) & 1ull) ? __uint_as_float(key[i1]) * invZ : 0.f;
      v[j] = (u32)h2u((_Float16)w0) | ((u32)h2u((_Float16)w1) << 16);
    }
    *(u32x4*)(wp + (g<<3)) = v;
  }
}

// ---------------- phase 3: dense PV GEMM, 2-phase dbuf with STATIC buffer names ----------------
// out^T[c,n] = sum_k Vc[c,k] * Wd[n,k].  128(M=ch) x 64(N=tok) tiles, K=NTOK, BK=64.
// Buffers are distinct named arrays + hand-unrolled x2 loop so LLVM can prove the
// STAGE(next) LDS writes don't alias the ds_reads of the compute buffer (round-10's
// runtime-indexed lds[cur] forced a conservative vmcnt(0) BEFORE compute -> regression).
#define STAGE_PV(LA, LB, KT)                                                  \
  {                                                                           \
    _Pragma("unroll")                                                         \
    for (int c=0;c<4;c++) {                                                   \
      int r  = (c<<5) + sr;                                                   \
      int ss = sslot ^ (r & 7);                                               \
      gload16(Ag + (size_t)r*NTOK + ((KT)<<6) + (ss<<3),                      \
              (char*)(LA) + (c<<12) + (wave<<10));                            \
    }                                                                         \
    _Pragma("unroll")                                                         \
    for (int c=0;c<2;c++) {                                                   \
      int r  = (c<<5) + sr;                                                   \
      int ss = sslot ^ (r & 7);                                               \
      gload16(Bg + (size_t)r*NTOK + ((KT)<<6) + (ss<<3),                      \
              (char*)(LB) + (c<<12) + (wave<<10));                            \
    }                                                                         \
  }

#define COMP_PV(LA, LB)                                                       \
  {                                                                           \
    _Pragma("unroll")                                                         \
    for (int ks=0;ks<2;ks++) {                                                \
      half8 af[4], bf[2];                                                     \
      const int kg = lane >> 4;                                               \
      const int rl = lane & 15;                                               \
      const int slot = (ks<<2) + kg;                                          \
      _Pragma("unroll")                                                       \
      for (int t=0;t<4;t++) {                                                 \
        int ar = (wm<<6) + (t<<4) + rl;                                       \
        af[t] = *(const half8*)&(LA)[ar*64 + ((slot ^ (ar&7))<<3)];           \
      }                                                                       \
      _Pragma("unroll")                                                       \
      for (int t=0;t<2;t++) {                                                 \
        int br = (wn<<5) + (t<<4) + rl;                                       \
        bf[t] = *(const half8*)&(LB)[br*64 + ((slot ^ (br&7))<<3)];           \
      }                                                                       \
      _Pragma("unroll")                                                       \
      for (int mt=0;mt<4;mt++)                                                \
        _Pragma("unroll")                                                     \
        for (int nt=0;nt<2;nt++)                                              \
          acc[mt][nt] = __builtin_amdgcn_mfma_f32_16x16x32_f16(af[mt], bf[nt], acc[mt][nt], 0,0,0); \
    }                                                                         \
  }

__global__ __launch_bounds__(256) void pv_gemm(
    const u16* __restrict__ Vc, const u16* __restrict__ Wd,
    float* __restrict__ out, int b_base, size_t wstride)
{
  __shared__ __align__(16) short lds_a0[128*64];   // 16 KB
  __shared__ __align__(16) short lds_a1[128*64];   // 16 KB
  __shared__ __align__(16) short lds_b0[64*64];    //  8 KB
  __shared__ __align__(16) short lds_b1[64*64];    //  8 KB
  const int tid  = threadIdx.x;
  const int lane = tid & 63;
  const int wave = tid >> 6;
  const int wm = wave >> 1, wn = wave & 1;
  const int b    = b_base + blockIdx.z;
  const int brow = blockIdx.x << 7;      // channel tile (0/128)
  const int bcol = blockIdx.y << 6;      // token tile (64-wide)

  const u16* Ag = Vc + (size_t)b*CH*NTOK + (size_t)brow*NTOK;
  const u16* Bg = Wd + (size_t)blockIdx.z*wstride + (size_t)bcol*NTOK;

  f32x4 acc[4][2];
  #pragma unroll
  for (int i=0;i<4;i++)
    #pragma unroll
    for (int j=0;j<2;j++) acc[i][j] = (f32x4)0.f;

  const int sr    = tid >> 3;
  const int sslot = tid & 7;

  STAGE_PV(lds_a0, lds_b0, 0);
  __syncthreads();
  for (int kt=0; kt<64; kt+=2) {
    if (kt+1 < 64) STAGE_PV(lds_a1, lds_b1, kt+1);   // in flight during compute(buf0)
    COMP_PV(lds_a0, lds_b0);
    __syncthreads();                                  // drains buf1 loads (post-compute)
    if (kt+2 < 64) STAGE_PV(lds_a0, lds_b0, kt+2);   // in flight during compute(buf1)
    COMP_PV(lds_a1, lds_b1);
    __syncthreads();                                  // drains buf0 loads (post-compute)
  }

  float* ob = out + (size_t)b*CH*NTOK;
  const int rl = lane & 15, rg = lane >> 4;
  #pragma unroll
  for (int mt=0;mt<4;mt++) {
    #pragma unroll
    for (int nt=0;nt<2;nt++) {
      int row = brow + (wm<<6) + (mt<<4) + (rg<<2);   // channel
      int col = bcol + (wn<<5) + (nt<<4) + rl;        // token
      #pragma unroll
      for (int r=0;r<4;r++)
        ob[(size_t)(row+r)*NTOK + col] = acc[mt][nt][r];
    }
  }
}

// ---------------- launcher ----------------
extern "C" void kernel_launch(void* const* d_in, const int* in_sizes, int n_in,
                              void* d_out, int out_size, void* d_ws, size_t ws_size,
                              hipStream_t stream)
{
  (void)in_sizes; (void)n_in; (void)out_size;
  const float* x  = (const float*)d_in[0];
  const float* Wq = (const float*)d_in[1];
  const float* Wk = (const float*)d_in[2];
  const float* Wv = (const float*)d_in[3];
  float* out = (float*)d_out;

  char* ws = (char*)d_ws;
  size_t off = 0;
  const size_t plane = (size_t)BATCH*NTOK*CH*2;       // 8.4 MB fp16 plane
  const size_t NN    = (size_t)NTOK*NTOK;             // 16.8M elements
  u16* Qh = (u16*)(ws + off); off += plane;
  u16* Kh = (u16*)(ws + off); off += plane;
  u16* Vc = (u16*)(ws + off); off += plane;
  u16* W3h = (u16*)(ws + off); off += (size_t)3*CH*CH*2;
  u16* W3l = (u16*)(ws + off); off += (size_t)3*CH*CH*2;
  // xT planes live only until proj_gemm completes; Wd/S overlap them afterwards.
  const size_t xt_base = off;
  u16* xTh = (u16*)(ws + xt_base);
  u16* xTl = (u16*)(ws + xt_base + plane);
  const size_t fullW_need = xt_base + (size_t)BATCH*NN*2 + NN*2;   // ~194 MiB
  const bool fullW = ws_size >= fullW_need;
  u16* Wd = (u16*)(ws + xt_base);
  u16* S  = (u16*)(ws + xt_base + (fullW ? (size_t)BATCH*NN*2 : NN*2));

  wsplit_kernel<<<dim3(64,3), 256, 0, stream>>>(Wq, Wk, Wv, W3h, W3l);
  xsplit_kernel<<<dim3(64,4,4), 256, 0, stream>>>(x, xTh, xTl);
  proj_gemm<<<dim3(32,2,12), 256, 0, stream>>>(xTh, xTl, W3h, W3l, Qh, Kh, Vc);

  if (fullW) {
    for (int b=0; b<BATCH; b++) {
      score_kernel<<<dim3(32,32), 256, 0, stream>>>(Qh, Kh, S, b);
      select_kernel<<<1024, 256, 0, stream>>>(S, Wd + (size_t)b*NN);
    }
    pv_gemm<<<dim3(2,64,4), 256, 0, stream>>>(Vc, Wd, out, 0, NN);
  } else {
    for (int b=0; b<BATCH; b++) {
      score_kernel<<<dim3(32,32), 256, 0, stream>>>(Qh, Kh, S, b);
      select_kernel<<<1024, 256, 0, stream>>>(S, Wd);
      pv_gemm<<<dim3(2,64,1), 256, 0, stream>>>(Vc, Wd, out, b, 0);
    }
  }
}

// Round 12
// 286.651 us; speedup vs baseline: 1.9536x; 1.0492x over previous
//
#include <hip/hip_runtime.h>
#include <stdint.h>

#define BATCH 4
#define CH    256
#define NTOK  4096
#define KSEL  409          // int(0.1 * 4096)

typedef unsigned short u16;
typedef unsigned int   u32;
typedef unsigned long long u64;

typedef __attribute__((ext_vector_type(8))) _Float16 half8;
typedef __attribute__((ext_vector_type(4))) _Float16 half4;
typedef __attribute__((ext_vector_type(4))) float f32x4;
typedef __attribute__((ext_vector_type(4))) u32 u32x4;
typedef __attribute__((ext_vector_type(2))) u32 u32x2;
typedef __attribute__((ext_vector_type(4))) float fl4;

// ---------------- helpers ----------------
__device__ inline u16 h2u(_Float16 h){ u16 u; __builtin_memcpy(&u,&h,2); return u; }
__device__ inline float u2f16(u32 v){ _Float16 h; u16 uu=(u16)v; __builtin_memcpy(&h,&uu,2); return (float)h; }
// monotone 16-bit fp16<->uint key transform (ascending)
__device__ inline float kinv16(u32 k){
  u32 v = (k & 0x8000u) ? (k & 0x7FFFu) : ((~k) & 0xFFFFu);
  return u2f16(v);
}
__device__ inline void gload16(const void* g, void* l){
  __builtin_amdgcn_global_load_lds((const __attribute__((address_space(1))) u32*)g,
                                   (__attribute__((address_space(3))) u32*)l, 16, 0, 0);
}

// ---------------- phase -1: W split ----------------
__global__ __launch_bounds__(256) void wsplit_kernel(
    const float* __restrict__ Wq, const float* __restrict__ Wk,
    const float* __restrict__ Wv, u16* __restrict__ W3h, u16* __restrict__ W3l)
{
  const int p = blockIdx.y;
  const float* W = (p==0)? Wq : (p==1)? Wk : Wv;
  const int idx = (blockIdx.x*256 + threadIdx.x) * 4;
  fl4 v = *(const fl4*)(W + idx);
  u32x2 vh, vl;
  #pragma unroll
  for (int q=0;q<2;q++) {
    _Float16 h0=(_Float16)v[q*2], h1=(_Float16)v[q*2+1];
    _Float16 l0=(_Float16)(v[q*2]-(float)h0), l1=(_Float16)(v[q*2+1]-(float)h1);
    vh[q] = (u32)h2u(h0) | ((u32)h2u(h1)<<16);
    vl[q] = (u32)h2u(l0) | ((u32)h2u(l1)<<16);
  }
  *(u32x2*)(W3h + p*CH*CH + idx) = vh;
  *(u32x2*)(W3l + p*CH*CH + idx) = vl;
}

// ---------------- phase 0a: x transpose + split ----------------
__global__ __launch_bounds__(256) void xsplit_kernel(
    const float* __restrict__ x, u16* __restrict__ xTh, u16* __restrict__ xTl)
{
  __shared__ float lds[64][65];
  const int tid = threadIdx.x;
  const int n0 = blockIdx.x << 6;
  const int c0 = blockIdx.y << 6;
  const int b  = blockIdx.z;
  const float* xb = x + (size_t)b*CH*NTOK;

  #pragma unroll
  for (int i=0;i<16;i++) {
    int c_l = (tid>>6) + (i<<2);
    int n_l = tid & 63;
    lds[c_l][n_l] = xb[(size_t)(c0+c_l)*NTOK + n0 + n_l];
  }
  __syncthreads();
  u16* oh = xTh + (size_t)b*NTOK*CH;
  u16* ol = xTl + (size_t)b*NTOK*CH;
  #pragma unroll
  for (int i=0;i<16;i++) {
    int n_l = (tid>>6) + (i<<2);
    int c_l = tid & 63;
    float v = lds[c_l][n_l];
    _Float16 h = (_Float16)v;
    _Float16 l = (_Float16)(v - (float)h);
    size_t o = (size_t)(n0+n_l)*CH + c0 + c_l;
    oh[o] = h2u(h);
    ol[o] = h2u(l);
  }
}

// ---------------- phase 0b: QKV projection GEMM ----------------
__global__ __launch_bounds__(256) void proj_gemm(
    const u16* __restrict__ xTh, const u16* __restrict__ xTl,
    const u16* __restrict__ W3h, const u16* __restrict__ W3l,
    u16* __restrict__ Qh, u16* __restrict__ Kh, u16* __restrict__ Vc)
{
  __shared__ __align__(16) short lds[4*128*64];   // ah, al, bh, bl (16KB each)
  short* lds_ah = lds;
  short* lds_al = lds + 128*64;
  short* lds_bh = lds + 2*128*64;
  short* lds_bl = lds + 3*128*64;

  const int tid  = threadIdx.x;
  const int lane = tid & 63;
  const int wave = tid >> 6;
  const int wm = wave >> 1, wn = wave & 1;
  const int brow = blockIdx.x << 7;     // token tile
  const int bcol = blockIdx.y << 7;     // out-channel tile
  const int z = blockIdx.z;             // b*3 + p
  const int b = z / 3, p = z - 3*b;

  const u16* Agh = xTh + ((size_t)b*NTOK + brow)*CH;
  const u16* Agl = xTl + ((size_t)b*NTOK + brow)*CH;
  const u16* Bgh = W3h + (size_t)p*CH*CH + (size_t)bcol*CH;
  const u16* Bgl = W3l + (size_t)p*CH*CH + (size_t)bcol*CH;

  f32x4 acc[4][4];
  #pragma unroll
  for (int i=0;i<4;i++)
    #pragma unroll
    for (int j=0;j<4;j++) acc[i][j] = (f32x4)0.f;

  const int sr    = tid >> 3;
  const int sslot = tid & 7;

  for (int kt=0; kt<4; kt++) {
    #pragma unroll
    for (int c=0;c<4;c++) {
      int r  = (c<<5) + sr;
      int ss = sslot ^ (r & 7);
      size_t goff = (size_t)r*CH + (kt<<6) + (ss<<3);
      int dst = (c<<12) + (wave<<10);
      gload16(Agh + goff, (char*)lds_ah + dst);
      gload16(Agl + goff, (char*)lds_al + dst);
      gload16(Bgh + goff, (char*)lds_bh + dst);
      gload16(Bgl + goff, (char*)lds_bl + dst);
    }
    __syncthreads();
    #pragma unroll
    for (int ks=0;ks<2;ks++) {
      half8 ah[4], al[4], bh[4], bl[4];
      const int kg = lane >> 4;
      const int rl = lane & 15;
      #pragma unroll
      for (int t=0;t<4;t++) {
        int ar = (wm<<6) + (t<<4) + rl;
        int slot = (ks<<2) + kg;
        int ao = ar*64 + ((slot ^ (ar&7))<<3);
        ah[t] = *(const half8*)&lds_ah[ao];
        al[t] = *(const half8*)&lds_al[ao];
        int br = (wn<<6) + (t<<4) + rl;
        int bo = br*64 + ((slot ^ (br&7))<<3);
        bh[t] = *(const half8*)&lds_bh[bo];
        bl[t] = *(const half8*)&lds_bl[bo];
      }
      #pragma unroll
      for (int mt=0;mt<4;mt++)
        #pragma unroll
        for (int nt=0;nt<4;nt++) {
          acc[mt][nt] = __builtin_amdgcn_mfma_f32_16x16x32_f16(ah[mt], bh[nt], acc[mt][nt], 0,0,0);
          acc[mt][nt] = __builtin_amdgcn_mfma_f32_16x16x32_f16(ah[mt], bl[nt], acc[mt][nt], 0,0,0);
          acc[mt][nt] = __builtin_amdgcn_mfma_f32_16x16x32_f16(al[mt], bh[nt], acc[mt][nt], 0,0,0);
        }
    }
    __syncthreads();
  }

  const int rl = lane & 15, rg = lane >> 4;
  if (p < 2) {
    u16* oh = ((p==0)? Qh : Kh) + (size_t)b*NTOK*CH;
    #pragma unroll
    for (int mt=0;mt<4;mt++) {
      #pragma unroll
      for (int nt=0;nt<4;nt++) {
        int n = brow + (wm<<6) + (mt<<4) + (rg<<2);
        int c = bcol + (wn<<6) + (nt<<4) + rl;
        #pragma unroll
        for (int r=0;r<4;r++)
          oh[(size_t)(n+r)*CH + c] = h2u((_Float16)acc[mt][nt][r]);
      }
    }
  } else {
    // V: transpose in LDS -> store channel-major Vc[b][d][n] coalesced
    u16* ldsT = (u16*)lds;                 // [128][136] u16
    #pragma unroll
    for (int mt=0;mt<4;mt++) {
      #pragma unroll
      for (int nt=0;nt<4;nt++) {
        int n_l = (wm<<6) + (mt<<4) + (rg<<2);
        int c_l = (wn<<6) + (nt<<4) + rl;
        half4 hv;
        #pragma unroll
        for (int r=0;r<4;r++) hv[r] = (_Float16)acc[mt][nt][r];
        *(half4*)&ldsT[c_l*136 + n_l] = hv;
      }
    }
    __syncthreads();
    u16* ov = Vc + (size_t)b*CH*NTOK + (size_t)bcol*NTOK + brow;
    #pragma unroll
    for (int i=0;i<32;i++) {
      int d_l = (tid>>6) + (i<<2);
      u32 v = *(const u32*)&ldsT[d_l*136 + (lane<<1)];
      *(u32*)(ov + (size_t)d_l*NTOK + (lane<<1)) = v;
    }
  }
}

// ============ counted-vmcnt pipeline macros (T4: never drain vmcnt to 0 mid-loop) ============
#define WAITV(S)  asm volatile("s_waitcnt " S ::: "memory")
#define RBAR()    __builtin_amdgcn_s_barrier()
#define SCHED0()  __builtin_amdgcn_sched_barrier(0)

// ---------------- phase 1: S = Q*K^T / 16, hi-only fp16, fp16 out, 2-deep pipeline ----------------
#define STAGE_SC(LA, LB, KT)                                                  \
  {                                                                           \
    _Pragma("unroll")                                                         \
    for (int c=0;c<4;c++) {                                                   \
      int r  = (c<<5) + sr;                                                   \
      int ss = sslot ^ (r & 7);                                               \
      size_t goff = (size_t)r*CH + ((KT)<<6) + (ss<<3);                       \
      gload16(Ag + goff, (char*)(LA) + (c<<12) + (wave<<10));                 \
      gload16(Bg + goff, (char*)(LB) + (c<<12) + (wave<<10));                 \
    }                                                                         \
  }

#define COMP_SC(LA, LB)                                                       \
  {                                                                           \
    _Pragma("unroll")                                                         \
    for (int ks=0;ks<2;ks++) {                                                \
      half8 af[4], bf[4];                                                     \
      const int kg = lane >> 4;                                               \
      const int rl = lane & 15;                                               \
      _Pragma("unroll")                                                       \
      for (int t=0;t<4;t++) {                                                 \
        int ar = (wm<<6) + (t<<4) + rl;                                       \
        int slot = (ks<<2) + kg;                                              \
        af[t] = *(const half8*)&(LA)[ar*64 + ((slot ^ (ar&7))<<3)];           \
        int br = (wn<<6) + (t<<4) + rl;                                       \
        bf[t] = *(const half8*)&(LB)[br*64 + ((slot ^ (br&7))<<3)];           \
      }                                                                       \
      _Pragma("unroll")                                                       \
      for (int mt=0;mt<4;mt++)                                                \
        _Pragma("unroll")                                                     \
        for (int nt=0;nt<4;nt++)                                              \
          acc[mt][nt] = __builtin_amdgcn_mfma_f32_16x16x32_f16(af[mt], bf[nt], acc[mt][nt], 0,0,0); \
    }                                                                         \
  }

__global__ __launch_bounds__(256) void score_kernel(
    const u16* __restrict__ Qh, const u16* __restrict__ Kh,
    u16* __restrict__ S, int b)
{
  __shared__ __align__(16) short lds_a0[128*64];
  __shared__ __align__(16) short lds_a1[128*64];
  __shared__ __align__(16) short lds_b0[128*64];
  __shared__ __align__(16) short lds_b1[128*64];
  const int tid  = threadIdx.x;
  const int lane = tid & 63;
  const int wave = tid >> 6;
  const int wm = wave >> 1, wn = wave & 1;
  const int brow = blockIdx.x << 7, bcol = blockIdx.y << 7;

  const u16* Ag = Qh + ((size_t)b*NTOK + brow)*CH;
  const u16* Bg = Kh + ((size_t)b*NTOK + bcol)*CH;

  f32x4 acc[4][4];
  #pragma unroll
  for (int i=0;i<4;i++)
    #pragma unroll
    for (int j=0;j<4;j++) acc[i][j] = (f32x4)0.f;

  const int sr    = tid >> 3;
  const int sslot = tid & 7;

  STAGE_SC(lds_a0, lds_b0, 0);
  STAGE_SC(lds_a1, lds_b1, 1);
  // t=0
  WAITV("vmcnt(8)"); RBAR(); SCHED0();
  COMP_SC(lds_a0, lds_b0);
  RBAR(); SCHED0();
  STAGE_SC(lds_a0, lds_b0, 2);
  // t=1
  WAITV("vmcnt(8)"); RBAR(); SCHED0();
  COMP_SC(lds_a1, lds_b1);
  RBAR(); SCHED0();
  STAGE_SC(lds_a1, lds_b1, 3);
  // t=2
  WAITV("vmcnt(8)"); RBAR(); SCHED0();
  COMP_SC(lds_a0, lds_b0);
  RBAR(); SCHED0();
  // t=3
  WAITV("vmcnt(0)"); RBAR(); SCHED0();
  COMP_SC(lds_a1, lds_b1);

  const int rl = lane & 15, rg = lane >> 4;
  #pragma unroll
  for (int mt=0;mt<4;mt++) {
    #pragma unroll
    for (int nt=0;nt<4;nt++) {
      int row = brow + (wm<<6) + (mt<<4) + (rg<<2);
      int col = bcol + (wn<<6) + (nt<<4) + rl;
      #pragma unroll
      for (int r=0;r<4;r++)
        S[(size_t)(row+r)*NTOK + col] = h2u((_Float16)(acc[mt][nt][r] * 0.0625f));
    }
  }
}

// ---------------- phase 2: exact per-row top-KSEL on fp16 scores ----------------
__global__ __launch_bounds__(256) void select_kernel(
    const u16* __restrict__ Sh, u16* __restrict__ Wd)
{
  __shared__ __align__(16) u32 hist[4][256];
  const int lane = threadIdx.x & 63;
  const int wave = threadIdx.x >> 6;
  const int row  = (blockIdx.x << 2) + wave;
  const u16* Srow = Sh + (size_t)row * NTOK + (lane << 6);

  u32 key[64];
  u32 umax = 0;
  #pragma unroll
  for (int g=0; g<8; ++g) {
    u32x4 q = *(const u32x4*)(Srow + (g<<3));
    #pragma unroll
    for (int j=0; j<4; ++j) {
      u32 w = q[j];
      u32 a = w & 0xFFFFu, bb = w >> 16;
      a  = (a  & 0x8000u) ? ((~a)  & 0xFFFFu) : (a  | 0x8000u);
      bb = (bb & 0x8000u) ? ((~bb) & 0xFFFFu) : (bb | 0x8000u);
      key[(g<<3)+(j<<1)  ] = a;
      key[(g<<3)+(j<<1)+1] = bb;
      umax = umax > a  ? umax : a;
      umax = umax > bb ? umax : bb;
    }
  }
  #pragma unroll
  for (int off=32; off; off>>=1) { u32 o = __shfl_xor(umax, off, 64); umax = o>umax ? o : umax; }
  const float m = kinv16(umax);

  u32 krem = KSEL, prefix = 0, cb = 0;
  #pragma unroll
  for (int pass=0; pass<2; ++pass) {
    const int shift = 8 - (pass<<3);           // 8 then 0
    #pragma unroll
    for (int i=0;i<4;i++) hist[wave][(i<<6)+lane] = 0u;
    __asm__ volatile("s_waitcnt lgkmcnt(0)" ::: "memory");
    if (pass == 0) {
      #pragma unroll
      for (int ch=0; ch<64; ch++) atomicAdd(&hist[wave][key[ch] >> 8], 1u);
    } else {
      const u32 b1 = prefix >> 8;
      #pragma unroll
      for (int ch=0; ch<64; ch++)
        if ((key[ch] >> 8) == b1) atomicAdd(&hist[wave][key[ch] & 255u], 1u);
    }
    __asm__ volatile("s_waitcnt lgkmcnt(0)" ::: "memory");
    u32x4 h = *(const u32x4*)&hist[wave][lane<<2];
    u32 tot = h[0]+h[1]+h[2]+h[3];
    u32 sfx = tot;
    #pragma unroll
    for (int off=1; off<64; off<<=1) {
      u32 v = __shfl_down(sfx, off, 64);
      if (lane + off < 64) sfx += v;
    }
    u32 s3 = (sfx - tot) + h[3];
    u32 s2 = s3 + h[2];
    u32 s1 = s2 + h[1];
    u32 s0 = s1 + h[0];
    u32 s4 = s3 - h[3];
    u32 kr = krem;
    u32 enc = 0;
    if (s0 >= kr && s1 < kr) enc = ((u32)((lane<<2)+0)<<22) | (h[0]<<9) | (kr - s1);
    if (s1 >= kr && s2 < kr) enc = ((u32)((lane<<2)+1)<<22) | (h[1]<<9) | (kr - s2);
    if (s2 >= kr && s3 < kr) enc = ((u32)((lane<<2)+2)<<22) | (h[2]<<9) | (kr - s3);
    if (s3 >= kr && s4 < kr) enc = ((u32)((lane<<2)+3)<<22) | (h[3]<<9) | (kr - s4);
    #pragma unroll
    for (int off=32; off; off>>=1) { u32 o = __shfl_xor(enc, off, 64); enc = (o>enc)? o:enc; }
    prefix |= (enc >> 22) << shift;
    cb      = (enc >> 9) & 0x1FFFu;
    krem    = enc & 0x1FFu;
  }
  const u32 tkey = prefix;                    // exact KSEL-th-largest fp16 key

  // selection bitmask
  u64 selb = 0;
  if (cb == krem) {
    #pragma unroll
    for (int ch=0; ch<64; ch++)
      if (key[ch] >= tkey) selb |= (1ull << ch);
  } else {
    const u64 ltmask = (1ull << lane) - 1ull;
    int eqbase = 0;
    #pragma unroll
    for (int ch=0; ch<64; ch++) {
      bool eq = (key[ch] == tkey);
      u64 eqm = __ballot(eq);
      bool sel = (key[ch] > tkey) || (eq && (eqbase + __popcll(eqm & ltmask)) < (int)krem);
      if (sel) selb |= (1ull << ch);
      eqbase += __popcll(eqm);
    }
  }

  // exp + denominator (cache e in key regs)
  float z = 0.f;
  #pragma unroll
  for (int ch=0; ch<64; ch++) {
    float e = __expf(kinv16(key[ch]) - m);
    if ((selb >> ch) & 1ull) z += e;
    key[ch] = __float_as_uint(e);
  }
  #pragma unroll
  for (int off=32; off; off>>=1) z += __shfl_xor(z, off, 64);
  const float invZ = 1.f / z;

  // vectorized dense weight row write (element = lane*64+ch)
  u16* wp = Wd + (size_t)row * NTOK + (lane << 6);
  #pragma unroll
  for (int g=0; g<8; ++g) {
    u32x4 v;
    #pragma unroll
    for (int j=0; j<4; ++j) {
      int i0 = (g<<3)+(j<<1), i1 = i0+1;
      float w0 = ((selb >> i0) & 1ull) ? __uint_as_float(key[i0]) * invZ : 0.f;
      float w1 = ((selb >> i1) & 1ull) ? __uint_as_float(key[i1]) * invZ : 0.f;
      v[j] = (u32)h2u((_Float16)w0) | ((u32)h2u((_Float16)w1) << 16);
    }
    *(u32x4*)(wp + (g<<3)) = v;
  }
}

// ---------------- phase 3: dense PV GEMM, 3-deep counted-vmcnt pipeline ----------------
// out^T[c,n] = sum_k Vc[c,k] * Wd[n,k].  128(M=ch) x 64(N=tok) tiles, K=NTOK, BK=64.
// 3 static buffers; per iter: vmcnt(12) [tile-t's 6 loads done, t+1/t+2 stay in flight]
// -> barrier -> COMP(t) -> barrier -> re-STAGE(t+3). vmcnt never drains to 0 mid-loop.
#define STAGE_PV(LA, LB, KT)                                                  \
  {                                                                           \
    _Pragma("unroll")                                                         \
    for (int c=0;c<4;c++) {                                                   \
      int r  = (c<<5) + sr;                                                   \
      int ss = sslot ^ (r & 7);                                               \
      gload16(Ag + (size_t)r*NTOK + ((KT)<<6) + (ss<<3),                      \
              (char*)(LA) + (c<<12) + (wave<<10));                            \
    }                                                                         \
    _Pragma("unroll")                                                         \
    for (int c=0;c<2;c++) {                                                   \
      int r  = (c<<5) + sr;                                                   \
      int ss = sslot ^ (r & 7);                                               \
      gload16(Bg + (size_t)r*NTOK + ((KT)<<6) + (ss<<3),                      \
              (char*)(LB) + (c<<12) + (wave<<10));                            \
    }                                                                         \
  }

#define COMP_PV(LA, LB)                                                       \
  {                                                                           \
    _Pragma("unroll")                                                         \
    for (int ks=0;ks<2;ks++) {                                                \
      half8 af[4], bf[2];                                                     \
      const int kg = lane >> 4;                                               \
      const int rl = lane & 15;                                               \
      const int slot = (ks<<2) + kg;                                          \
      _Pragma("unroll")                                                       \
      for (int t=0;t<4;t++) {                                                 \
        int ar = (wm<<6) + (t<<4) + rl;                                       \
        af[t] = *(const half8*)&(LA)[ar*64 + ((slot ^ (ar&7))<<3)];           \
      }                                                                       \
      _Pragma("unroll")                                                       \
      for (int t=0;t<2;t++) {                                                 \
        int br = (wn<<5) + (t<<4) + rl;                                       \
        bf[t] = *(const half8*)&(LB)[br*64 + ((slot ^ (br&7))<<3)];           \
      }                                                                       \
      _Pragma("unroll")                                                       \
      for (int mt=0;mt<4;mt++)                                                \
        _Pragma("unroll")                                                     \
        for (int nt=0;nt<2;nt++)                                              \
          acc[mt][nt] = __builtin_amdgcn_mfma_f32_16x16x32_f16(af[mt], bf[nt], acc[mt][nt], 0,0,0); \
    }                                                                         \
  }

#define PV_ITER(LA, LB, VM, TS)                                               \
  WAITV(VM); RBAR(); SCHED0();                                                \
  COMP_PV(LA, LB);                                                            \
  RBAR(); SCHED0();                                                           \
  if ((TS) < 64) STAGE_PV(LA, LB, TS);

__global__ __launch_bounds__(256) void pv_gemm(
    const u16* __restrict__ Vc, const u16* __restrict__ Wd,
    float* __restrict__ out, int b_base, size_t wstride)
{
  __shared__ __align__(16) short lds_a0[128*64];   // 16 KB x3
  __shared__ __align__(16) short lds_a1[128*64];
  __shared__ __align__(16) short lds_a2[128*64];
  __shared__ __align__(16) short lds_b0[64*64];    //  8 KB x3
  __shared__ __align__(16) short lds_b1[64*64];
  __shared__ __align__(16) short lds_b2[64*64];
  const int tid  = threadIdx.x;
  const int lane = tid & 63;
  const int wave = tid >> 6;
  const int wm = wave >> 1, wn = wave & 1;
  const int b    = b_base + blockIdx.z;
  const int brow = blockIdx.x << 7;      // channel tile (0/128)
  const int bcol = blockIdx.y << 6;      // token tile (64-wide)

  const u16* Ag = Vc + (size_t)b*CH*NTOK + (size_t)brow*NTOK;
  const u16* Bg = Wd + (size_t)blockIdx.z*wstride + (size_t)bcol*NTOK;

  f32x4 acc[4][2];
  #pragma unroll
  for (int i=0;i<4;i++)
    #pragma unroll
    for (int j=0;j<2;j++) acc[i][j] = (f32x4)0.f;

  const int sr    = tid >> 3;
  const int sslot = tid & 7;

  STAGE_PV(lds_a0, lds_b0, 0);
  STAGE_PV(lds_a1, lds_b1, 1);
  STAGE_PV(lds_a2, lds_b2, 2);

  for (int g=0; g<20; ++g) {               // t = 0..59
    const int t = g*3;
    PV_ITER(lds_a0, lds_b0, "vmcnt(12)", t+3);
    PV_ITER(lds_a1, lds_b1, "vmcnt(12)", t+4);
    PV_ITER(lds_a2, lds_b2, "vmcnt(12)", t+5);
  }
  // t=60 (stages 63), 61, 62, 63 tail
  PV_ITER(lds_a0, lds_b0, "vmcnt(12)", 63);
  PV_ITER(lds_a1, lds_b1, "vmcnt(12)", 64);
  PV_ITER(lds_a2, lds_b2, "vmcnt(6)",  64);
  WAITV("vmcnt(0)"); RBAR(); SCHED0();
  COMP_PV(lds_a0, lds_b0);

  float* ob = out + (size_t)b*CH*NTOK;
  const int rl = lane & 15, rg = lane >> 4;
  #pragma unroll
  for (int mt=0;mt<4;mt++) {
    #pragma unroll
    for (int nt=0;nt<2;nt++) {
      int row = brow + (wm<<6) + (mt<<4) + (rg<<2);   // channel
      int col = bcol + (wn<<5) + (nt<<4) + rl;        // token
      #pragma unroll
      for (int r=0;r<4;r++)
        ob[(size_t)(row+r)*NTOK + col] = acc[mt][nt][r];
    }
  }
}

// ---------------- launcher ----------------
extern "C" void kernel_launch(void* const* d_in, const int* in_sizes, int n_in,
                              void* d_out, int out_size, void* d_ws, size_t ws_size,
                              hipStream_t stream)
{
  (void)in_sizes; (void)n_in; (void)out_size;
  const float* x  = (const float*)d_in[0];
  const float* Wq = (const float*)d_in[1];
  const float* Wk = (const float*)d_in[2];
  const float* Wv = (const float*)d_in[3];
  float* out = (float*)d_out;

  char* ws = (char*)d_ws;
  size_t off = 0;
  const size_t plane = (size_t)BATCH*NTOK*CH*2;       // 8.4 MB fp16 plane
  const size_t NN    = (size_t)NTOK*NTOK;             // 16.8M elements
  u16* Qh = (u16*)(ws + off); off += plane;
  u16* Kh = (u16*)(ws + off); off += plane;
  u16* Vc = (u16*)(ws + off); off += plane;
  u16* W3h = (u16*)(ws + off); off += (size_t)3*CH*CH*2;
  u16* W3l = (u16*)(ws + off); off += (size_t)3*CH*CH*2;
  // xT planes live only until proj_gemm completes; Wd/S overlap them afterwards.
  const size_t xt_base = off;
  u16* xTh = (u16*)(ws + xt_base);
  u16* xTl = (u16*)(ws + xt_base + plane);
  const size_t fullW_need = xt_base + (size_t)BATCH*NN*2 + NN*2;   // ~194 MiB
  const bool fullW = ws_size >= fullW_need;
  u16* Wd = (u16*)(ws + xt_base);
  u16* S  = (u16*)(ws + xt_base + (fullW ? (size_t)BATCH*NN*2 : NN*2));

  wsplit_kernel<<<dim3(64,3), 256, 0, stream>>>(Wq, Wk, Wv, W3h, W3l);
  xsplit_kernel<<<dim3(64,4,4), 256, 0, stream>>>(x, xTh, xTl);
  proj_gemm<<<dim3(32,2,12), 256, 0, stream>>>(xTh, xTl, W3h, W3l, Qh, Kh, Vc);

  if (fullW) {
    for (int b=0; b<BATCH; b++) {
      score_kernel<<<dim3(32,32), 256, 0, stream>>>(Qh, Kh, S, b);
      select_kernel<<<1024, 256, 0, stream>>>(S, Wd + (size_t)b*NN);
    }
    pv_gemm<<<dim3(2,64,4), 256, 0, stream>>>(Vc, Wd, out, 0, NN);
  } else {
    for (int b=0; b<BATCH; b++) {
      score_kernel<<<dim3(32,32), 256, 0, stream>>>(Qh, Kh, S, b);
      select_kernel<<<1024, 256, 0, stream>>>(S, Wd);
      pv_gemm<<<dim3(2,64,1), 256, 0, stream>>>(Vc, Wd, out, b, 0);
    }
  }
}

// Round 13
// 284.888 us; speedup vs baseline: 1.9657x; 1.0062x over previous
//
#include <hip/hip_runtime.h>
#include <stdint.h>

#define BATCH 4
#define CH    256
#define NTOK  4096
#define KSEL  409          // int(0.1 * 4096)

typedef unsigned short u16;
typedef unsigned int   u32;
typedef unsigned long long u64;

typedef __attribute__((ext_vector_type(8))) _Float16 half8;
typedef __attribute__((ext_vector_type(4))) _Float16 half4;
typedef __attribute__((ext_vector_type(4))) float f32x4;
typedef __attribute__((ext_vector_type(4))) u32 u32x4;
typedef __attribute__((ext_vector_type(2))) u32 u32x2;
typedef __attribute__((ext_vector_type(4))) float fl4;

// ---------------- helpers ----------------
__device__ inline u16 h2u(_Float16 h){ u16 u; __builtin_memcpy(&u,&h,2); return u; }
__device__ inline float u2f16(u32 v){ _Float16 h; u16 uu=(u16)v; __builtin_memcpy(&h,&uu,2); return (float)h; }
// monotone 16-bit fp16<->uint key transform (ascending)
__device__ inline float kinv16(u32 k){
  u32 v = (k & 0x8000u) ? (k & 0x7FFFu) : ((~k) & 0xFFFFu);
  return u2f16(v);
}
__device__ inline void gload16(const void* g, void* l){
  __builtin_amdgcn_global_load_lds((const __attribute__((address_space(1))) u32*)g,
                                   (__attribute__((address_space(3))) u32*)l, 16, 0, 0);
}

// ---------------- phase -1: W split ----------------
__global__ __launch_bounds__(256) void wsplit_kernel(
    const float* __restrict__ Wq, const float* __restrict__ Wk,
    const float* __restrict__ Wv, u16* __restrict__ W3h, u16* __restrict__ W3l)
{
  const int p = blockIdx.y;
  const float* W = (p==0)? Wq : (p==1)? Wk : Wv;
  const int idx = (blockIdx.x*256 + threadIdx.x) * 4;
  fl4 v = *(const fl4*)(W + idx);
  u32x2 vh, vl;
  #pragma unroll
  for (int q=0;q<2;q++) {
    _Float16 h0=(_Float16)v[q*2], h1=(_Float16)v[q*2+1];
    _Float16 l0=(_Float16)(v[q*2]-(float)h0), l1=(_Float16)(v[q*2+1]-(float)h1);
    vh[q] = (u32)h2u(h0) | ((u32)h2u(h1)<<16);
    vl[q] = (u32)h2u(l0) | ((u32)h2u(l1)<<16);
  }
  *(u32x2*)(W3h + p*CH*CH + idx) = vh;
  *(u32x2*)(W3l + p*CH*CH + idx) = vl;
}

// ---------------- phase 0a: x transpose + split ----------------
__global__ __launch_bounds__(256) void xsplit_kernel(
    const float* __restrict__ x, u16* __restrict__ xTh, u16* __restrict__ xTl)
{
  __shared__ float lds[64][65];
  const int tid = threadIdx.x;
  const int n0 = blockIdx.x << 6;
  const int c0 = blockIdx.y << 6;
  const int b  = blockIdx.z;
  const float* xb = x + (size_t)b*CH*NTOK;

  #pragma unroll
  for (int i=0;i<16;i++) {
    int c_l = (tid>>6) + (i<<2);
    int n_l = tid & 63;
    lds[c_l][n_l] = xb[(size_t)(c0+c_l)*NTOK + n0 + n_l];
  }
  __syncthreads();
  u16* oh = xTh + (size_t)b*NTOK*CH;
  u16* ol = xTl + (size_t)b*NTOK*CH;
  #pragma unroll
  for (int i=0;i<16;i++) {
    int n_l = (tid>>6) + (i<<2);
    int c_l = tid & 63;
    float v = lds[c_l][n_l];
    _Float16 h = (_Float16)v;
    _Float16 l = (_Float16)(v - (float)h);
    size_t o = (size_t)(n0+n_l)*CH + c0 + c_l;
    oh[o] = h2u(h);
    ol[o] = h2u(l);
  }
}

// ---------------- phase 0b: QKV projection GEMM ----------------
__global__ __launch_bounds__(256) void proj_gemm(
    const u16* __restrict__ xTh, const u16* __restrict__ xTl,
    const u16* __restrict__ W3h, const u16* __restrict__ W3l,
    u16* __restrict__ Qh, u16* __restrict__ Kh, u16* __restrict__ Vc)
{
  __shared__ __align__(16) short lds[4*128*64];   // ah, al, bh, bl (16KB each)
  short* lds_ah = lds;
  short* lds_al = lds + 128*64;
  short* lds_bh = lds + 2*128*64;
  short* lds_bl = lds + 3*128*64;

  const int tid  = threadIdx.x;
  const int lane = tid & 63;
  const int wave = tid >> 6;
  const int wm = wave >> 1, wn = wave & 1;
  const int brow = blockIdx.x << 7;     // token tile
  const int bcol = blockIdx.y << 7;     // out-channel tile
  const int z = blockIdx.z;             // b*3 + p
  const int b = z / 3, p = z - 3*b;

  const u16* Agh = xTh + ((size_t)b*NTOK + brow)*CH;
  const u16* Agl = xTl + ((size_t)b*NTOK + brow)*CH;
  const u16* Bgh = W3h + (size_t)p*CH*CH + (size_t)bcol*CH;
  const u16* Bgl = W3l + (size_t)p*CH*CH + (size_t)bcol*CH;

  f32x4 acc[4][4];
  #pragma unroll
  for (int i=0;i<4;i++)
    #pragma unroll
    for (int j=0;j<4;j++) acc[i][j] = (f32x4)0.f;

  const int sr    = tid >> 3;
  const int sslot = tid & 7;

  for (int kt=0; kt<4; kt++) {
    #pragma unroll
    for (int c=0;c<4;c++) {
      int r  = (c<<5) + sr;
      int ss = sslot ^ (r & 7);
      size_t goff = (size_t)r*CH + (kt<<6) + (ss<<3);
      int dst = (c<<12) + (wave<<10);
      gload16(Agh + goff, (char*)lds_ah + dst);
      gload16(Agl + goff, (char*)lds_al + dst);
      gload16(Bgh + goff, (char*)lds_bh + dst);
      gload16(Bgl + goff, (char*)lds_bl + dst);
    }
    __syncthreads();
    #pragma unroll
    for (int ks=0;ks<2;ks++) {
      half8 ah[4], al[4], bh[4], bl[4];
      const int kg = lane >> 4;
      const int rl = lane & 15;
      #pragma unroll
      for (int t=0;t<4;t++) {
        int ar = (wm<<6) + (t<<4) + rl;
        int slot = (ks<<2) + kg;
        int ao = ar*64 + ((slot ^ (ar&7))<<3);
        ah[t] = *(const half8*)&lds_ah[ao];
        al[t] = *(const half8*)&lds_al[ao];
        int br = (wn<<6) + (t<<4) + rl;
        int bo = br*64 + ((slot ^ (br&7))<<3);
        bh[t] = *(const half8*)&lds_bh[bo];
        bl[t] = *(const half8*)&lds_bl[bo];
      }
      #pragma unroll
      for (int mt=0;mt<4;mt++)
        #pragma unroll
        for (int nt=0;nt<4;nt++) {
          acc[mt][nt] = __builtin_amdgcn_mfma_f32_16x16x32_f16(ah[mt], bh[nt], acc[mt][nt], 0,0,0);
          acc[mt][nt] = __builtin_amdgcn_mfma_f32_16x16x32_f16(ah[mt], bl[nt], acc[mt][nt], 0,0,0);
          acc[mt][nt] = __builtin_amdgcn_mfma_f32_16x16x32_f16(al[mt], bh[nt], acc[mt][nt], 0,0,0);
        }
    }
    __syncthreads();
  }

  const int rl = lane & 15, rg = lane >> 4;
  if (p < 2) {
    u16* oh = ((p==0)? Qh : Kh) + (size_t)b*NTOK*CH;
    #pragma unroll
    for (int mt=0;mt<4;mt++) {
      #pragma unroll
      for (int nt=0;nt<4;nt++) {
        int n = brow + (wm<<6) + (mt<<4) + (rg<<2);
        int c = bcol + (wn<<6) + (nt<<4) + rl;
        #pragma unroll
        for (int r=0;r<4;r++)
          oh[(size_t)(n+r)*CH + c] = h2u((_Float16)acc[mt][nt][r]);
      }
    }
  } else {
    // V: transpose in LDS -> store channel-major Vc[b][d][n] coalesced
    u16* ldsT = (u16*)lds;                 // [128][136] u16
    #pragma unroll
    for (int mt=0;mt<4;mt++) {
      #pragma unroll
      for (int nt=0;nt<4;nt++) {
        int n_l = (wm<<6) + (mt<<4) + (rg<<2);
        int c_l = (wn<<6) + (nt<<4) + rl;
        half4 hv;
        #pragma unroll
        for (int r=0;r<4;r++) hv[r] = (_Float16)acc[mt][nt][r];
        *(half4*)&ldsT[c_l*136 + n_l] = hv;
      }
    }
    __syncthreads();
    u16* ov = Vc + (size_t)b*CH*NTOK + (size_t)bcol*NTOK + brow;
    #pragma unroll
    for (int i=0;i<32;i++) {
      int d_l = (tid>>6) + (i<<2);
      u32 v = *(const u32*)&ldsT[d_l*136 + (lane<<1)];
      *(u32*)(ov + (size_t)d_l*NTOK + (lane<<1)) = v;
    }
  }
}

// ============ counted-vmcnt pipeline macros (T4: never drain vmcnt to 0 mid-loop) ============
#define WAITV(S)  asm volatile("s_waitcnt " S ::: "memory")
#define RBAR()    __builtin_amdgcn_s_barrier()
#define SCHED0()  __builtin_amdgcn_sched_barrier(0)

// ---------------- phase 1: S = Q*K^T / 16, hi-only fp16, fp16 out, 2-deep pipeline ----------------
#define STAGE_SC(LA, LB, KT)                                                  \
  {                                                                           \
    _Pragma("unroll")                                                         \
    for (int c=0;c<4;c++) {                                                   \
      int r  = (c<<5) + sr;                                                   \
      int ss = sslot ^ (r & 7);                                               \
      size_t goff = (size_t)r*CH + ((KT)<<6) + (ss<<3);                       \
      gload16(Ag + goff, (char*)(LA) + (c<<12) + (wave<<10));                 \
      gload16(Bg + goff, (char*)(LB) + (c<<12) + (wave<<10));                 \
    }                                                                         \
  }

#define COMP_SC(LA, LB)                                                       \
  {                                                                           \
    _Pragma("unroll")                                                         \
    for (int ks=0;ks<2;ks++) {                                                \
      half8 af[4], bf[4];                                                     \
      const int kg = lane >> 4;                                               \
      const int rl = lane & 15;                                               \
      _Pragma("unroll")                                                       \
      for (int t=0;t<4;t++) {                                                 \
        int ar = (wm<<6) + (t<<4) + rl;                                       \
        int slot = (ks<<2) + kg;                                              \
        af[t] = *(const half8*)&(LA)[ar*64 + ((slot ^ (ar&7))<<3)];           \
        int br = (wn<<6) + (t<<4) + rl;                                       \
        bf[t] = *(const half8*)&(LB)[br*64 + ((slot ^ (br&7))<<3)];           \
      }                                                                       \
      _Pragma("unroll")                                                       \
      for (int mt=0;mt<4;mt++)                                                \
        _Pragma("unroll")                                                     \
        for (int nt=0;nt<4;nt++)                                              \
          acc[mt][nt] = __builtin_amdgcn_mfma_f32_16x16x32_f16(af[mt], bf[nt], acc[mt][nt], 0,0,0); \
    }                                                                         \
  }

__global__ __launch_bounds__(256) void score_kernel(
    const u16* __restrict__ Qh, const u16* __restrict__ Kh,
    u16* __restrict__ S, int b)
{
  __shared__ __align__(16) short lds_a0[128*64];
  __shared__ __align__(16) short lds_a1[128*64];
  __shared__ __align__(16) short lds_b0[128*64];
  __shared__ __align__(16) short lds_b1[128*64];
  const int tid  = threadIdx.x;
  const int lane = tid & 63;
  const int wave = tid >> 6;
  const int wm = wave >> 1, wn = wave & 1;
  const int brow = blockIdx.x << 7, bcol = blockIdx.y << 7;

  const u16* Ag = Qh + ((size_t)b*NTOK + brow)*CH;
  const u16* Bg = Kh + ((size_t)b*NTOK + bcol)*CH;

  f32x4 acc[4][4];
  #pragma unroll
  for (int i=0;i<4;i++)
    #pragma unroll
    for (int j=0;j<4;j++) acc[i][j] = (f32x4)0.f;

  const int sr    = tid >> 3;
  const int sslot = tid & 7;

  STAGE_SC(lds_a0, lds_b0, 0);
  STAGE_SC(lds_a1, lds_b1, 1);
  // t=0
  WAITV("vmcnt(8)"); RBAR(); SCHED0();
  COMP_SC(lds_a0, lds_b0);
  RBAR(); SCHED0();
  STAGE_SC(lds_a0, lds_b0, 2);
  // t=1
  WAITV("vmcnt(8)"); RBAR(); SCHED0();
  COMP_SC(lds_a1, lds_b1);
  RBAR(); SCHED0();
  STAGE_SC(lds_a1, lds_b1, 3);
  // t=2
  WAITV("vmcnt(8)"); RBAR(); SCHED0();
  COMP_SC(lds_a0, lds_b0);
  RBAR(); SCHED0();
  // t=3
  WAITV("vmcnt(0)"); RBAR(); SCHED0();
  COMP_SC(lds_a1, lds_b1);

  const int rl = lane & 15, rg = lane >> 4;
  #pragma unroll
  for (int mt=0;mt<4;mt++) {
    #pragma unroll
    for (int nt=0;nt<4;nt++) {
      int row = brow + (wm<<6) + (mt<<4) + (rg<<2);
      int col = bcol + (wn<<6) + (nt<<4) + rl;
      #pragma unroll
      for (int r=0;r<4;r++)
        S[(size_t)(row+r)*NTOK + col] = h2u((_Float16)(acc[mt][nt][r] * 0.0625f));
    }
  }
}

// ---------------- phase 2: exact per-row top-KSEL on fp16 scores ----------------
// one wave per row; 64 16-bit keys/lane, COALESCED layout: element = g*512 + lane*8 + j
// (lane reads 16B at lane*16 within each 1KB stripe -> fully coalesced).
// 2 radix-8 histogram passes exhaust the 16-bit key space: tkey exact.
__global__ __launch_bounds__(256) void select_kernel(
    const u16* __restrict__ Sh, u16* __restrict__ Wd)
{
  __shared__ __align__(16) u32 hist[4][256];
  const int lane = threadIdx.x & 63;
  const int wave = threadIdx.x >> 6;
  const int row  = (blockIdx.x << 2) + wave;
  const u16* Srow = Sh + (size_t)row * NTOK + (lane << 3);   // lane offset within stripe

  u32 key[64];
  u32 umax = 0;
  #pragma unroll
  for (int g=0; g<8; ++g) {
    u32x4 q = *(const u32x4*)(Srow + (g<<9));   // stripe g: 512 elements
    #pragma unroll
    for (int j=0; j<4; ++j) {
      u32 w = q[j];
      u32 a = w & 0xFFFFu, bb = w >> 16;
      a  = (a  & 0x8000u) ? ((~a)  & 0xFFFFu) : (a  | 0x8000u);
      bb = (bb & 0x8000u) ? ((~bb) & 0xFFFFu) : (bb | 0x8000u);
      key[(g<<3)+(j<<1)  ] = a;
      key[(g<<3)+(j<<1)+1] = bb;
      umax = umax > a  ? umax : a;
      umax = umax > bb ? umax : bb;
    }
  }
  #pragma unroll
  for (int off=32; off; off>>=1) { u32 o = __shfl_xor(umax, off, 64); umax = o>umax ? o : umax; }
  const float m = kinv16(umax);

  u32 krem = KSEL, prefix = 0, cb = 0;
  #pragma unroll
  for (int pass=0; pass<2; ++pass) {
    const int shift = 8 - (pass<<3);           // 8 then 0
    #pragma unroll
    for (int i=0;i<4;i++) hist[wave][(i<<6)+lane] = 0u;
    __asm__ volatile("s_waitcnt lgkmcnt(0)" ::: "memory");
    if (pass == 0) {
      #pragma unroll
      for (int ch=0; ch<64; ch++) atomicAdd(&hist[wave][key[ch] >> 8], 1u);
    } else {
      const u32 b1 = prefix >> 8;
      #pragma unroll
      for (int ch=0; ch<64; ch++)
        if ((key[ch] >> 8) == b1) atomicAdd(&hist[wave][key[ch] & 255u], 1u);
    }
    __asm__ volatile("s_waitcnt lgkmcnt(0)" ::: "memory");
    u32x4 h = *(const u32x4*)&hist[wave][lane<<2];
    u32 tot = h[0]+h[1]+h[2]+h[3];
    u32 sfx = tot;
    #pragma unroll
    for (int off=1; off<64; off<<=1) {
      u32 v = __shfl_down(sfx, off, 64);
      if (lane + off < 64) sfx += v;
    }
    u32 s3 = (sfx - tot) + h[3];
    u32 s2 = s3 + h[2];
    u32 s1 = s2 + h[1];
    u32 s0 = s1 + h[0];
    u32 s4 = s3 - h[3];
    u32 kr = krem;
    u32 enc = 0;
    if (s0 >= kr && s1 < kr) enc = ((u32)((lane<<2)+0)<<22) | (h[0]<<9) | (kr - s1);
    if (s1 >= kr && s2 < kr) enc = ((u32)((lane<<2)+1)<<22) | (h[1]<<9) | (kr - s2);
    if (s2 >= kr && s3 < kr) enc = ((u32)((lane<<2)+2)<<22) | (h[2]<<9) | (kr - s3);
    if (s3 >= kr && s4 < kr) enc = ((u32)((lane<<2)+3)<<22) | (h[3]<<9) | (kr - s4);
    #pragma unroll
    for (int off=32; off; off>>=1) { u32 o = __shfl_xor(enc, off, 64); enc = (o>enc)? o:enc; }
    prefix |= (enc >> 22) << shift;
    cb      = (enc >> 9) & 0x1FFFu;
    krem    = enc & 0x1FFu;
  }
  const u32 tkey = prefix;                    // exact KSEL-th-largest fp16 key

  // selection bitmask
  u64 selb = 0;
  if (cb == krem) {
    #pragma unroll
    for (int ch=0; ch<64; ch++)
      if (key[ch] >= tkey) selb |= (1ull << ch);
  } else {
    const u64 ltmask = (1ull << lane) - 1ull;
    int eqbase = 0;
    #pragma unroll
    for (int ch=0; ch<64; ch++) {
      bool eq = (key[ch] == tkey);
      u64 eqm = __ballot(eq);
      bool sel = (key[ch] > tkey) || (eq && (eqbase + __popcll(eqm & ltmask)) < (int)krem);
      if (sel) selb |= (1ull << ch);
      eqbase += __popcll(eqm);
    }
  }

  // exp + denominator (cache e in key regs)
  float z = 0.f;
  #pragma unroll
  for (int ch=0; ch<64; ch++) {
    float e = __expf(kinv16(key[ch]) - m);
    if ((selb >> ch) & 1ull) z += e;
    key[ch] = __float_as_uint(e);
  }
  #pragma unroll
  for (int off=32; off; off>>=1) z += __shfl_xor(z, off, 64);
  const float invZ = 1.f / z;

  // coalesced dense weight row write (mirror of the read layout)
  u16* wp = Wd + (size_t)row * NTOK + (lane << 3);
  #pragma unroll
  for (int g=0; g<8; ++g) {
    u32x4 v;
    #pragma unroll
    for (int j=0; j<4; ++j) {
      int i0 = (g<<3)+(j<<1), i1 = i0+1;
      float w0 = ((selb >> i0) & 1ull) ? __uint_as_float(key[i0]) * invZ : 0.f;
      float w1 = ((selb >> i1) & 1ull) ? __uint_as_float(key[i1]) * invZ : 0.f;
      v[j] = (u32)h2u((_Float16)w0) | ((u32)h2u((_Float16)w1) << 16);
    }
    *(u32x4*)(wp + (g<<9)) = v;
  }
}

// ---------------- phase 3: dense PV GEMM, 2-deep counted-vmcnt pipeline ----------------
// out^T[c,n] = sum_k Vc[c,k] * Wd[n,k].  128(M=ch) x 64(N=tok) tiles, K=NTOK, BK=64.
// 48KB LDS -> 3 blocks/CU (more HBM request streams). vmcnt(6): tile-t's 6 loads done,
// tile t+1's stay in flight across the barrier; never drained to 0 mid-loop.
#define STAGE_PV(LA, LB, KT)                                                  \
  {                                                                           \
    _Pragma("unroll")                                                         \
    for (int c=0;c<4;c++) {                                                   \
      int r  = (c<<5) + sr;                                                   \
      int ss = sslot ^ (r & 7);                                               \
      gload16(Ag + (size_t)r*NTOK + ((KT)<<6) + (ss<<3),                      \
              (char*)(LA) + (c<<12) + (wave<<10));                            \
    }                                                                         \
    _Pragma("unroll")                                                         \
    for (int c=0;c<2;c++) {                                                   \
      int r  = (c<<5) + sr;                                                   \
      int ss = sslot ^ (r & 7);                                               \
      gload16(Bg + (size_t)r*NTOK + ((KT)<<6) + (ss<<3),                      \
              (char*)(LB) + (c<<12) + (wave<<10));                            \
    }                                                                         \
  }

#define COMP_PV(LA, LB)                                                       \
  {                                                                           \
    _Pragma("unroll")                                                         \
    for (int ks=0;ks<2;ks++) {                                                \
      half8 af[4], bf[2];                                                     \
      const int kg = lane >> 4;                                               \
      const int rl = lane & 15;                                               \
      const int slot = (ks<<2) + kg;                                          \
      _Pragma("unroll")                                                       \
      for (int t=0;t<4;t++) {                                                 \
        int ar = (wm<<6) + (t<<4) + rl;                                       \
        af[t] = *(const half8*)&(LA)[ar*64 + ((slot ^ (ar&7))<<3)];           \
      }                                                                       \
      _Pragma("unroll")                                                       \
      for (int t=0;t<2;t++) {                                                 \
        int br = (wn<<5) + (t<<4) + rl;                                       \
        bf[t] = *(const half8*)&(LB)[br*64 + ((slot ^ (br&7))<<3)];           \
      }                                                                       \
      _Pragma("unroll")                                                       \
      for (int mt=0;mt<4;mt++)                                                \
        _Pragma("unroll")                                                     \
        for (int nt=0;nt<2;nt++)                                              \
          acc[mt][nt] = __builtin_amdgcn_mfma_f32_16x16x32_f16(af[mt], bf[nt], acc[mt][nt], 0,0,0); \
    }                                                                         \
  }

#define PV_ITER(LA, LB, VM, TS)                                               \
  WAITV(VM); RBAR(); SCHED0();                                                \
  COMP_PV(LA, LB);                                                            \
  RBAR(); SCHED0();                                                           \
  if ((TS) < 64) STAGE_PV(LA, LB, TS);

__global__ __launch_bounds__(256) void pv_gemm(
    const u16* __restrict__ Vc, const u16* __restrict__ Wd,
    float* __restrict__ out, int b_base, size_t wstride)
{
  __shared__ __align__(16) short lds_a0[128*64];   // 16 KB x2
  __shared__ __align__(16) short lds_a1[128*64];
  __shared__ __align__(16) short lds_b0[64*64];    //  8 KB x2
  __shared__ __align__(16) short lds_b1[64*64];
  const int tid  = threadIdx.x;
  const int lane = tid & 63;
  const int wave = tid >> 6;
  const int wm = wave >> 1, wn = wave & 1;
  const int b    = b_base + blockIdx.z;
  const int brow = blockIdx.x << 7;      // channel tile (0/128)
  const int bcol = blockIdx.y << 6;      // token tile (64-wide)

  const u16* Ag = Vc + (size_t)b*CH*NTOK + (size_t)brow*NTOK;
  const u16* Bg = Wd + (size_t)blockIdx.z*wstride + (size_t)bcol*NTOK;

  f32x4 acc[4][2];
  #pragma unroll
  for (int i=0;i<4;i++)
    #pragma unroll
    for (int j=0;j<2;j++) acc[i][j] = (f32x4)0.f;

  const int sr    = tid >> 3;
  const int sslot = tid & 7;

  STAGE_PV(lds_a0, lds_b0, 0);
  STAGE_PV(lds_a1, lds_b1, 1);

  for (int g=0; g<31; ++g) {               // t = 0..61
    const int t = g*2;
    PV_ITER(lds_a0, lds_b0, "vmcnt(6)", t+2);
    PV_ITER(lds_a1, lds_b1, "vmcnt(6)", t+3);
  }
  // tail: t=62 (6 outstanding from t=63), t=63
  WAITV("vmcnt(6)"); RBAR(); SCHED0();
  COMP_PV(lds_a0, lds_b0);
  RBAR(); SCHED0();
  WAITV("vmcnt(0)"); RBAR(); SCHED0();
  COMP_PV(lds_a1, lds_b1);

  float* ob = out + (size_t)b*CH*NTOK;
  const int rl = lane & 15, rg = lane >> 4;
  #pragma unroll
  for (int mt=0;mt<4;mt++) {
    #pragma unroll
    for (int nt=0;nt<2;nt++) {
      int row = brow + (wm<<6) + (mt<<4) + (rg<<2);   // channel
      int col = bcol + (wn<<5) + (nt<<4) + rl;        // token
      #pragma unroll
      for (int r=0;r<4;r++)
        ob[(size_t)(row+r)*NTOK + col] = acc[mt][nt][r];
    }
  }
}

// ---------------- launcher ----------------
extern "C" void kernel_launch(void* const* d_in, const int* in_sizes, int n_in,
                              void* d_out, int out_size, void* d_ws, size_t ws_size,
                              hipStream_t stream)
{
  (void)in_sizes; (void)n_in; (void)out_size;
  const float* x  = (const float*)d_in[0];
  const float* Wq = (const float*)d_in[1];
  const float* Wk = (const float*)d_in[2];
  const float* Wv = (const float*)d_in[3];
  float* out = (float*)d_out;

  char* ws = (char*)d_ws;
  size_t off = 0;
  const size_t plane = (size_t)BATCH*NTOK*CH*2;       // 8.4 MB fp16 plane
  const size_t NN    = (size_t)NTOK*NTOK;             // 16.8M elements
  u16* Qh = (u16*)(ws + off); off += plane;
  u16* Kh = (u16*)(ws + off); off += plane;
  u16* Vc = (u16*)(ws + off); off += plane;
  u16* W3h = (u16*)(ws + off); off += (size_t)3*CH*CH*2;
  u16* W3l = (u16*)(ws + off); off += (size_t)3*CH*CH*2;
  // xT planes live only until proj_gemm completes; Wd/S overlap them afterwards.
  const size_t xt_base = off;
  u16* xTh = (u16*)(ws + xt_base);
  u16* xTl = (u16*)(ws + xt_base + plane);
  const size_t fullW_need = xt_base + (size_t)BATCH*NN*2 + NN*2;   // ~194 MiB
  const bool fullW = ws_size >= fullW_need;
  u16* Wd = (u16*)(ws + xt_base);
  u16* S  = (u16*)(ws + xt_base + (fullW ? (size_t)BATCH*NN*2 : NN*2));

  wsplit_kernel<<<dim3(64,3), 256, 0, stream>>>(Wq, Wk, Wv, W3h, W3l);
  xsplit_kernel<<<dim3(64,4,4), 256, 0, stream>>>(x, xTh, xTl);
  proj_gemm<<<dim3(32,2,12), 256, 0, stream>>>(xTh, xTl, W3h, W3l, Qh, Kh, Vc);

  if (fullW) {
    for (int b=0; b<BATCH; b++) {
      score_kernel<<<dim3(32,32), 256, 0, stream>>>(Qh, Kh, S, b);
      select_kernel<<<1024, 256, 0, stream>>>(S, Wd + (size_t)b*NN);
    }
    pv_gemm<<<dim3(2,64,4), 256, 0, stream>>>(Vc, Wd, out, 0, NN);
  } else {
    for (int b=0; b<BATCH; b++) {
      score_kernel<<<dim3(32,32), 256, 0, stream>>>(Qh, Kh, S, b);
      select_kernel<<<1024, 256, 0, stream>>>(S, Wd);
      pv_gemm<<<dim3(2,64,1), 256, 0, stream>>>(Vc, Wd, out, b, 0);
    }
  }
}

// Round 14
// 227.853 us; speedup vs baseline: 2.4578x; 1.2503x over previous
//
#include <hip/hip_runtime.h>
#include <stdint.h>

#define BATCH 4
#define CH    256
#define NTOK  4096
#define KSEL  409          // int(0.1 * 4096)

typedef unsigned short u16;
typedef unsigned int   u32;
typedef unsigned long long u64;

typedef __attribute__((ext_vector_type(8))) _Float16 half8;
typedef __attribute__((ext_vector_type(4))) _Float16 half4;
typedef __attribute__((ext_vector_type(4))) float f32x4;
typedef __attribute__((ext_vector_type(4))) u32 u32x4;
typedef __attribute__((ext_vector_type(2))) u32 u32x2;
typedef __attribute__((ext_vector_type(4))) float fl4;

// ---------------- helpers ----------------
__device__ inline u16 h2u(_Float16 h){ u16 u; __builtin_memcpy(&u,&h,2); return u; }
__device__ inline float u2f16(u32 v){ _Float16 h; u16 uu=(u16)v; __builtin_memcpy(&h,&uu,2); return (float)h; }
// monotone 16-bit fp16<->uint key transform (ascending)
__device__ inline float kinv16(u32 k){
  u32 v = (k & 0x8000u) ? (k & 0x7FFFu) : ((~k) & 0xFFFFu);
  return u2f16(v);
}
__device__ inline void gload16(const void* g, void* l){
  __builtin_amdgcn_global_load_lds((const __attribute__((address_space(1))) u32*)g,
                                   (__attribute__((address_space(3))) u32*)l, 16, 0, 0);
}

// ---------------- phase -1: W split ----------------
__global__ __launch_bounds__(256) void wsplit_kernel(
    const float* __restrict__ Wq, const float* __restrict__ Wk,
    const float* __restrict__ Wv, u16* __restrict__ W3h, u16* __restrict__ W3l)
{
  const int p = blockIdx.y;
  const float* W = (p==0)? Wq : (p==1)? Wk : Wv;
  const int idx = (blockIdx.x*256 + threadIdx.x) * 4;
  fl4 v = *(const fl4*)(W + idx);
  u32x2 vh, vl;
  #pragma unroll
  for (int q=0;q<2;q++) {
    _Float16 h0=(_Float16)v[q*2], h1=(_Float16)v[q*2+1];
    _Float16 l0=(_Float16)(v[q*2]-(float)h0), l1=(_Float16)(v[q*2+1]-(float)h1);
    vh[q] = (u32)h2u(h0) | ((u32)h2u(h1)<<16);
    vl[q] = (u32)h2u(l0) | ((u32)h2u(l1)<<16);
  }
  *(u32x2*)(W3h + p*CH*CH + idx) = vh;
  *(u32x2*)(W3l + p*CH*CH + idx) = vl;
}

// ---------------- phase 0a: x transpose + split ----------------
__global__ __launch_bounds__(256) void xsplit_kernel(
    const float* __restrict__ x, u16* __restrict__ xTh, u16* __restrict__ xTl)
{
  __shared__ float lds[64][65];
  const int tid = threadIdx.x;
  const int n0 = blockIdx.x << 6;
  const int c0 = blockIdx.y << 6;
  const int b  = blockIdx.z;
  const float* xb = x + (size_t)b*CH*NTOK;

  #pragma unroll
  for (int i=0;i<16;i++) {
    int c_l = (tid>>6) + (i<<2);
    int n_l = tid & 63;
    lds[c_l][n_l] = xb[(size_t)(c0+c_l)*NTOK + n0 + n_l];
  }
  __syncthreads();
  u16* oh = xTh + (size_t)b*NTOK*CH;
  u16* ol = xTl + (size_t)b*NTOK*CH;
  #pragma unroll
  for (int i=0;i<16;i++) {
    int n_l = (tid>>6) + (i<<2);
    int c_l = tid & 63;
    float v = lds[c_l][n_l];
    _Float16 h = (_Float16)v;
    _Float16 l = (_Float16)(v - (float)h);
    size_t o = (size_t)(n0+n_l)*CH + c0 + c_l;
    oh[o] = h2u(h);
    ol[o] = h2u(l);
  }
}

// ---------------- phase 0b: QKV projection GEMM ----------------
__global__ __launch_bounds__(256) void proj_gemm(
    const u16* __restrict__ xTh, const u16* __restrict__ xTl,
    const u16* __restrict__ W3h, const u16* __restrict__ W3l,
    u16* __restrict__ Qh, u16* __restrict__ Kh, u16* __restrict__ Vc)
{
  __shared__ __align__(16) short lds[4*128*64];   // ah, al, bh, bl (16KB each)
  short* lds_ah = lds;
  short* lds_al = lds + 128*64;
  short* lds_bh = lds + 2*128*64;
  short* lds_bl = lds + 3*128*64;

  const int tid  = threadIdx.x;
  const int lane = tid & 63;
  const int wave = tid >> 6;
  const int wm = wave >> 1, wn = wave & 1;
  const int brow = blockIdx.x << 7;     // token tile
  const int bcol = blockIdx.y << 7;     // out-channel tile
  const int z = blockIdx.z;             // b*3 + p
  const int b = z / 3, p = z - 3*b;

  const u16* Agh = xTh + ((size_t)b*NTOK + brow)*CH;
  const u16* Agl = xTl + ((size_t)b*NTOK + brow)*CH;
  const u16* Bgh = W3h + (size_t)p*CH*CH + (size_t)bcol*CH;
  const u16* Bgl = W3l + (size_t)p*CH*CH + (size_t)bcol*CH;

  f32x4 acc[4][4];
  #pragma unroll
  for (int i=0;i<4;i++)
    #pragma unroll
    for (int j=0;j<4;j++) acc[i][j] = (f32x4)0.f;

  const int sr    = tid >> 3;
  const int sslot = tid & 7;

  for (int kt=0; kt<4; kt++) {
    #pragma unroll
    for (int c=0;c<4;c++) {
      int r  = (c<<5) + sr;
      int ss = sslot ^ (r & 7);
      size_t goff = (size_t)r*CH + (kt<<6) + (ss<<3);
      int dst = (c<<12) + (wave<<10);
      gload16(Agh + goff, (char*)lds_ah + dst);
      gload16(Agl + goff, (char*)lds_al + dst);
      gload16(Bgh + goff, (char*)lds_bh + dst);
      gload16(Bgl + goff, (char*)lds_bl + dst);
    }
    __syncthreads();
    #pragma unroll
    for (int ks=0;ks<2;ks++) {
      half8 ah[4], al[4], bh[4], bl[4];
      const int kg = lane >> 4;
      const int rl = lane & 15;
      #pragma unroll
      for (int t=0;t<4;t++) {
        int ar = (wm<<6) + (t<<4) + rl;
        int slot = (ks<<2) + kg;
        int ao = ar*64 + ((slot ^ (ar&7))<<3);
        ah[t] = *(const half8*)&lds_ah[ao];
        al[t] = *(const half8*)&lds_al[ao];
        int br = (wn<<6) + (t<<4) + rl;
        int bo = br*64 + ((slot ^ (br&7))<<3);
        bh[t] = *(const half8*)&lds_bh[bo];
        bl[t] = *(const half8*)&lds_bl[bo];
      }
      #pragma unroll
      for (int mt=0;mt<4;mt++)
        #pragma unroll
        for (int nt=0;nt<4;nt++) {
          acc[mt][nt] = __builtin_amdgcn_mfma_f32_16x16x32_f16(ah[mt], bh[nt], acc[mt][nt], 0,0,0);
          acc[mt][nt] = __builtin_amdgcn_mfma_f32_16x16x32_f16(ah[mt], bl[nt], acc[mt][nt], 0,0,0);
          acc[mt][nt] = __builtin_amdgcn_mfma_f32_16x16x32_f16(al[mt], bh[nt], acc[mt][nt], 0,0,0);
        }
    }
    __syncthreads();
  }

  const int rl = lane & 15, rg = lane >> 4;
  if (p < 2) {
    u16* oh = ((p==0)? Qh : Kh) + (size_t)b*NTOK*CH;
    #pragma unroll
    for (int mt=0;mt<4;mt++) {
      #pragma unroll
      for (int nt=0;nt<4;nt++) {
        int n = brow + (wm<<6) + (mt<<4) + (rg<<2);
        int c = bcol + (wn<<6) + (nt<<4) + rl;
        #pragma unroll
        for (int r=0;r<4;r++)
          oh[(size_t)(n+r)*CH + c] = h2u((_Float16)acc[mt][nt][r]);
      }
    }
  } else {
    // V: transpose in LDS -> store channel-major Vc[b][d][n] coalesced
    u16* ldsT = (u16*)lds;                 // [128][136] u16
    #pragma unroll
    for (int mt=0;mt<4;mt++) {
      #pragma unroll
      for (int nt=0;nt<4;nt++) {
        int n_l = (wm<<6) + (mt<<4) + (rg<<2);
        int c_l = (wn<<6) + (nt<<4) + rl;
        half4 hv;
        #pragma unroll
        for (int r=0;r<4;r++) hv[r] = (_Float16)acc[mt][nt][r];
        *(half4*)&ldsT[c_l*136 + n_l] = hv;
      }
    }
    __syncthreads();
    u16* ov = Vc + (size_t)b*CH*NTOK + (size_t)bcol*NTOK + brow;
    #pragma unroll
    for (int i=0;i<32;i++) {
      int d_l = (tid>>6) + (i<<2);
      u32 v = *(const u32*)&ldsT[d_l*136 + (lane<<1)];
      *(u32*)(ov + (size_t)d_l*NTOK + (lane<<1)) = v;
    }
  }
}

// ============ counted-vmcnt pipeline macros (T4: never drain vmcnt to 0 mid-loop) ============
#define WAITV(S)  asm volatile("s_waitcnt " S ::: "memory")
#define RBAR()    __builtin_amdgcn_s_barrier()
#define SCHED0()  __builtin_amdgcn_sched_barrier(0)

// ---------------- phase 1: S = Q*K^T / 16, hi-only fp16, fp16 out, 2-deep pipeline ----------------
#define STAGE_SC(LA, LB, KT)                                                  \
  {                                                                           \
    _Pragma("unroll")                                                         \
    for (int c=0;c<4;c++) {                                                   \
      int r  = (c<<5) + sr;                                                   \
      int ss = sslot ^ (r & 7);                                               \
      size_t goff = (size_t)r*CH + ((KT)<<6) + (ss<<3);                       \
      gload16(Ag + goff, (char*)(LA) + (c<<12) + (wave<<10));                 \
      gload16(Bg + goff, (char*)(LB) + (c<<12) + (wave<<10));                 \
    }                                                                         \
  }

#define COMP_SC(LA, LB)                                                       \
  {                                                                           \
    _Pragma("unroll")                                                         \
    for (int ks=0;ks<2;ks++) {                                                \
      half8 af[4], bf[4];                                                     \
      const int kg = lane >> 4;                                               \
      const int rl = lane & 15;                                               \
      _Pragma("unroll")                                                       \
      for (int t=0;t<4;t++) {                                                 \
        int ar = (wm<<6) + (t<<4) + rl;                                       \
        int slot = (ks<<2) + kg;                                              \
        af[t] = *(const half8*)&(LA)[ar*64 + ((slot ^ (ar&7))<<3)];           \
        int br = (wn<<6) + (t<<4) + rl;                                       \
        bf[t] = *(const half8*)&(LB)[br*64 + ((slot ^ (br&7))<<3)];           \
      }                                                                       \
      _Pragma("unroll")                                                       \
      for (int mt=0;mt<4;mt++)                                                \
        _Pragma("unroll")                                                     \
        for (int nt=0;nt<4;nt++)                                              \
          acc[mt][nt] = __builtin_amdgcn_mfma_f32_16x16x32_f16(af[mt], bf[nt], acc[mt][nt], 0,0,0); \
    }                                                                         \
  }

__global__ __launch_bounds__(256) void score_kernel(
    const u16* __restrict__ Qh, const u16* __restrict__ Kh,
    u16* __restrict__ S, int b_base, size_t sstride)
{
  __shared__ __align__(16) short lds_a0[128*64];
  __shared__ __align__(16) short lds_a1[128*64];
  __shared__ __align__(16) short lds_b0[128*64];
  __shared__ __align__(16) short lds_b1[128*64];
  const int tid  = threadIdx.x;
  const int lane = tid & 63;
  const int wave = tid >> 6;
  const int wm = wave >> 1, wn = wave & 1;
  const int brow = blockIdx.x << 7, bcol = blockIdx.y << 7;
  const int b = b_base + blockIdx.z;
  u16* Sb = S + (size_t)blockIdx.z * sstride;

  const u16* Ag = Qh + ((size_t)b*NTOK + brow)*CH;
  const u16* Bg = Kh + ((size_t)b*NTOK + bcol)*CH;

  f32x4 acc[4][4];
  #pragma unroll
  for (int i=0;i<4;i++)
    #pragma unroll
    for (int j=0;j<4;j++) acc[i][j] = (f32x4)0.f;

  const int sr    = tid >> 3;
  const int sslot = tid & 7;

  STAGE_SC(lds_a0, lds_b0, 0);
  STAGE_SC(lds_a1, lds_b1, 1);
  // t=0
  WAITV("vmcnt(8)"); RBAR(); SCHED0();
  COMP_SC(lds_a0, lds_b0);
  RBAR(); SCHED0();
  STAGE_SC(lds_a0, lds_b0, 2);
  // t=1
  WAITV("vmcnt(8)"); RBAR(); SCHED0();
  COMP_SC(lds_a1, lds_b1);
  RBAR(); SCHED0();
  STAGE_SC(lds_a1, lds_b1, 3);
  // t=2
  WAITV("vmcnt(8)"); RBAR(); SCHED0();
  COMP_SC(lds_a0, lds_b0);
  RBAR(); SCHED0();
  // t=3
  WAITV("vmcnt(0)"); RBAR(); SCHED0();
  COMP_SC(lds_a1, lds_b1);

  const int rl = lane & 15, rg = lane >> 4;
  #pragma unroll
  for (int mt=0;mt<4;mt++) {
    #pragma unroll
    for (int nt=0;nt<4;nt++) {
      int row = brow + (wm<<6) + (mt<<4) + (rg<<2);
      int col = bcol + (wn<<6) + (nt<<4) + rl;
      #pragma unroll
      for (int r=0;r<4;r++)
        Sb[(size_t)(row+r)*NTOK + col] = h2u((_Float16)(acc[mt][nt][r] * 0.0625f));
    }
  }
}

// ---------------- phase 2: exact per-row top-KSEL on fp16 scores, IN-PLACE S->W ----------------
// one wave per row; 64 16-bit keys/lane, coalesced (element = g*512 + lane*8 + j).
// Each thread fully reads its row-slice into registers BEFORE writing the weight back to the
// SAME addresses (per-thread same-byte read->write: race-free). W aliases S -> pv reads L3-hot.
// 2 radix-8 histogram passes exhaust the 16-bit key space: tkey exact.
__global__ __launch_bounds__(256) void select_kernel(u16* Sh, size_t sstride)
{
  __shared__ __align__(16) u32 hist[4][256];
  const int lane = threadIdx.x & 63;
  const int wave = threadIdx.x >> 6;
  const int row  = (blockIdx.x << 2) + wave;
  u16* Srow = Sh + (size_t)blockIdx.y * sstride + (size_t)row * NTOK + (lane << 3);

  u32 key[64];
  u32 umax = 0;
  #pragma unroll
  for (int g=0; g<8; ++g) {
    u32x4 q = *(const u32x4*)(Srow + (g<<9));   // stripe g: 512 elements
    #pragma unroll
    for (int j=0; j<4; ++j) {
      u32 w = q[j];
      u32 a = w & 0xFFFFu, bb = w >> 16;
      a  = (a  & 0x8000u) ? ((~a)  & 0xFFFFu) : (a  | 0x8000u);
      bb = (bb & 0x8000u) ? ((~bb) & 0xFFFFu) : (bb | 0x8000u);
      key[(g<<3)+(j<<1)  ] = a;
      key[(g<<3)+(j<<1)+1] = bb;
      umax = umax > a  ? umax : a;
      umax = umax > bb ? umax : bb;
    }
  }
  #pragma unroll
  for (int off=32; off; off>>=1) { u32 o = __shfl_xor(umax, off, 64); umax = o>umax ? o : umax; }
  const float m = kinv16(umax);

  u32 krem = KSEL, prefix = 0, cb = 0;
  #pragma unroll
  for (int pass=0; pass<2; ++pass) {
    const int shift = 8 - (pass<<3);           // 8 then 0
    #pragma unroll
    for (int i=0;i<4;i++) hist[wave][(i<<6)+lane] = 0u;
    __asm__ volatile("s_waitcnt lgkmcnt(0)" ::: "memory");
    if (pass == 0) {
      #pragma unroll
      for (int ch=0; ch<64; ch++) atomicAdd(&hist[wave][key[ch] >> 8], 1u);
    } else {
      const u32 b1 = prefix >> 8;
      #pragma unroll
      for (int ch=0; ch<64; ch++)
        if ((key[ch] >> 8) == b1) atomicAdd(&hist[wave][key[ch] & 255u], 1u);
    }
    __asm__ volatile("s_waitcnt lgkmcnt(0)" ::: "memory");
    u32x4 h = *(const u32x4*)&hist[wave][lane<<2];
    u32 tot = h[0]+h[1]+h[2]+h[3];
    u32 sfx = tot;
    #pragma unroll
    for (int off=1; off<64; off<<=1) {
      u32 v = __shfl_down(sfx, off, 64);
      if (lane + off < 64) sfx += v;
    }
    u32 s3 = (sfx - tot) + h[3];
    u32 s2 = s3 + h[2];
    u32 s1 = s2 + h[1];
    u32 s0 = s1 + h[0];
    u32 s4 = s3 - h[3];
    u32 kr = krem;
    u32 enc = 0;
    if (s0 >= kr && s1 < kr) enc = ((u32)((lane<<2)+0)<<22) | (h[0]<<9) | (kr - s1);
    if (s1 >= kr && s2 < kr) enc = ((u32)((lane<<2)+1)<<22) | (h[1]<<9) | (kr - s2);
    if (s2 >= kr && s3 < kr) enc = ((u32)((lane<<2)+2)<<22) | (h[2]<<9) | (kr - s3);
    if (s3 >= kr && s4 < kr) enc = ((u32)((lane<<2)+3)<<22) | (h[3]<<9) | (kr - s4);
    #pragma unroll
    for (int off=32; off; off>>=1) { u32 o = __shfl_xor(enc, off, 64); enc = (o>enc)? o:enc; }
    prefix |= (enc >> 22) << shift;
    cb      = (enc >> 9) & 0x1FFFu;
    krem    = enc & 0x1FFu;
  }
  const u32 tkey = prefix;                    // exact KSEL-th-largest fp16 key

  // selection bitmask
  u64 selb = 0;
  if (cb == krem) {
    #pragma unroll
    for (int ch=0; ch<64; ch++)
      if (key[ch] >= tkey) selb |= (1ull << ch);
  } else {
    const u64 ltmask = (1ull << lane) - 1ull;
    int eqbase = 0;
    #pragma unroll
    for (int ch=0; ch<64; ch++) {
      bool eq = (key[ch] == tkey);
      u64 eqm = __ballot(eq);
      bool sel = (key[ch] > tkey) || (eq && (eqbase + __popcll(eqm & ltmask)) < (int)krem);
      if (sel) selb |= (1ull << ch);
      eqbase += __popcll(eqm);
    }
  }

  // exp + denominator (cache e in key regs)
  float z = 0.f;
  #pragma unroll
  for (int ch=0; ch<64; ch++) {
    float e = __expf(kinv16(key[ch]) - m);
    if ((selb >> ch) & 1ull) z += e;
    key[ch] = __float_as_uint(e);
  }
  #pragma unroll
  for (int off=32; off; off>>=1) z += __shfl_xor(z, off, 64);
  const float invZ = 1.f / z;

  // coalesced IN-PLACE weight write (same addresses the row was read from)
  #pragma unroll
  for (int g=0; g<8; ++g) {
    u32x4 v;
    #pragma unroll
    for (int j=0; j<4; ++j) {
      int i0 = (g<<3)+(j<<1), i1 = i0+1;
      float w0 = ((selb >> i0) & 1ull) ? __uint_as_float(key[i0]) * invZ : 0.f;
      float w1 = ((selb >> i1) & 1ull) ? __uint_as_float(key[i1]) * invZ : 0.f;
      v[j] = (u32)h2u((_Float16)w0) | ((u32)h2u((_Float16)w1) << 16);
    }
    *(u32x4*)(Srow + (g<<9)) = v;
  }
}

// ---------------- phase 3: dense PV GEMM, 2-deep counted-vmcnt pipeline ----------------
// out^T[c,n] = sum_k Vc[c,k] * Wd[n,k].  128(M=ch) x 64(N=tok) tiles, K=NTOK, BK=64.
// Wd aliases S: freshly rewritten by select -> L3-resident at launch.
#define STAGE_PV(LA, LB, KT)                                                  \
  {                                                                           \
    _Pragma("unroll")                                                         \
    for (int c=0;c<4;c++) {                                                   \
      int r  = (c<<5) + sr;                                                   \
      int ss = sslot ^ (r & 7);                                               \
      gload16(Ag + (size_t)r*NTOK + ((KT)<<6) + (ss<<3),                      \
              (char*)(LA) + (c<<12) + (wave<<10));                            \
    }                                                                         \
    _Pragma("unroll")                                                         \
    for (int c=0;c<2;c++) {                                                   \
      int r  = (c<<5) + sr;                                                   \
      int ss = sslot ^ (r & 7);                                               \
      gload16(Bg + (size_t)r*NTOK + ((KT)<<6) + (ss<<3),                      \
              (char*)(LB) + (c<<12) + (wave<<10));                            \
    }                                                                         \
  }

#define COMP_PV(LA, LB)                                                       \
  {                                                                           \
    _Pragma("unroll")                                                         \
    for (int ks=0;ks<2;ks++) {                                                \
      half8 af[4], bf[2];                                                     \
      const int kg = lane >> 4;                                               \
      const int rl = lane & 15;                                               \
      const int slot = (ks<<2) + kg;                                          \
      _Pragma("unroll")                                                       \
      for (int t=0;t<4;t++) {                                                 \
        int ar = (wm<<6) + (t<<4) + rl;                                       \
        af[t] = *(const half8*)&(LA)[ar*64 + ((slot ^ (ar&7))<<3)];           \
      }                                                                       \
      _Pragma("unroll")                                                       \
      for (int t=0;t<2;t++) {                                                 \
        int br = (wn<<5) + (t<<4) + rl;                                       \
        bf[t] = *(const half8*)&(LB)[br*64 + ((slot ^ (br&7))<<3)];           \
      }                                                                       \
      _Pragma("unroll")                                                       \
      for (int mt=0;mt<4;mt++)                                                \
        _Pragma("unroll")                                                     \
        for (int nt=0;nt<2;nt++)                                              \
          acc[mt][nt] = __builtin_amdgcn_mfma_f32_16x16x32_f16(af[mt], bf[nt], acc[mt][nt], 0,0,0); \
    }                                                                         \
  }

#define PV_ITER(LA, LB, VM, TS)                                               \
  WAITV(VM); RBAR(); SCHED0();                                                \
  COMP_PV(LA, LB);                                                            \
  RBAR(); SCHED0();                                                           \
  if ((TS) < 64) STAGE_PV(LA, LB, TS);

__global__ __launch_bounds__(256) void pv_gemm(
    const u16* __restrict__ Vc, const u16* __restrict__ Wd,
    float* __restrict__ out, int b_base, size_t wstride)
{
  __shared__ __align__(16) short lds_a0[128*64];   // 16 KB x2
  __shared__ __align__(16) short lds_a1[128*64];
  __shared__ __align__(16) short lds_b0[64*64];    //  8 KB x2
  __shared__ __align__(16) short lds_b1[64*64];
  const int tid  = threadIdx.x;
  const int lane = tid & 63;
  const int wave = tid >> 6;
  const int wm = wave >> 1, wn = wave & 1;
  const int b    = b_base + blockIdx.z;
  const int brow = blockIdx.x << 7;      // channel tile (0/128)
  const int bcol = blockIdx.y << 6;      // token tile (64-wide)

  const u16* Ag = Vc + (size_t)b*CH*NTOK + (size_t)brow*NTOK;
  const u16* Bg = Wd + (size_t)blockIdx.z*wstride + (size_t)bcol*NTOK;

  f32x4 acc[4][2];
  #pragma unroll
  for (int i=0;i<4;i++)
    #pragma unroll
    for (int j=0;j<2;j++) acc[i][j] = (f32x4)0.f;

  const int sr    = tid >> 3;
  const int sslot = tid & 7;

  STAGE_PV(lds_a0, lds_b0, 0);
  STAGE_PV(lds_a1, lds_b1, 1);

  for (int g=0; g<31; ++g) {               // t = 0..61
    const int t = g*2;
    PV_ITER(lds_a0, lds_b0, "vmcnt(6)", t+2);
    PV_ITER(lds_a1, lds_b1, "vmcnt(6)", t+3);
  }
  // tail: t=62, t=63
  WAITV("vmcnt(6)"); RBAR(); SCHED0();
  COMP_PV(lds_a0, lds_b0);
  RBAR(); SCHED0();
  WAITV("vmcnt(0)"); RBAR(); SCHED0();
  COMP_PV(lds_a1, lds_b1);

  float* ob = out + (size_t)b*CH*NTOK;
  const int rl = lane & 15, rg = lane >> 4;
  #pragma unroll
  for (int mt=0;mt<4;mt++) {
    #pragma unroll
    for (int nt=0;nt<2;nt++) {
      int row = brow + (wm<<6) + (mt<<4) + (rg<<2);   // channel
      int col = bcol + (wn<<5) + (nt<<4) + rl;        // token
      #pragma unroll
      for (int r=0;r<4;r++)
        ob[(size_t)(row+r)*NTOK + col] = acc[mt][nt][r];
    }
  }
}

// ---------------- launcher ----------------
extern "C" void kernel_launch(void* const* d_in, const int* in_sizes, int n_in,
                              void* d_out, int out_size, void* d_ws, size_t ws_size,
                              hipStream_t stream)
{
  (void)in_sizes; (void)n_in; (void)out_size;
  const float* x  = (const float*)d_in[0];
  const float* Wq = (const float*)d_in[1];
  const float* Wk = (const float*)d_in[2];
  const float* Wv = (const float*)d_in[3];
  float* out = (float*)d_out;

  char* ws = (char*)d_ws;
  size_t off = 0;
  const size_t plane = (size_t)BATCH*NTOK*CH*2;       // 8.4 MB fp16 plane
  const size_t NN    = (size_t)NTOK*NTOK;             // 16.8M elements
  u16* Qh = (u16*)(ws + off); off += plane;
  u16* Kh = (u16*)(ws + off); off += plane;
  u16* Vc = (u16*)(ws + off); off += plane;
  u16* W3h = (u16*)(ws + off); off += (size_t)3*CH*CH*2;
  u16* W3l = (u16*)(ws + off); off += (size_t)3*CH*CH*2;
  // xT planes live only until proj_gemm completes; S (== W, in-place) overlaps them after.
  const size_t xt_base = off;
  u16* xTh = (u16*)(ws + xt_base);
  u16* xTl = (u16*)(ws + xt_base + plane);
  u16* S   = (u16*)(ws + xt_base);
  const size_t full_need = xt_base + (size_t)BATCH*NN*2;   // ~160 MiB: S[4] fp16, W aliases S
  const bool full = ws_size >= full_need;

  wsplit_kernel<<<dim3(64,3), 256, 0, stream>>>(Wq, Wk, Wv, W3h, W3l);
  xsplit_kernel<<<dim3(64,4,4), 256, 0, stream>>>(x, xTh, xTl);
  proj_gemm<<<dim3(32,2,12), 256, 0, stream>>>(xTh, xTl, W3h, W3l, Qh, Kh, Vc);

  if (full) {
    // all scores -> all selects (in-place S->W) -> pv ; last-touched 134MB = W -> L3-hot for pv
    score_kernel<<<dim3(32,32,4), 256, 0, stream>>>(Qh, Kh, S, 0, NN);
    select_kernel<<<dim3(1024,4), 256, 0, stream>>>(S, NN);
    pv_gemm<<<dim3(2,64,4), 256, 0, stream>>>(Vc, S, out, 0, NN);
  } else {
    // low-ws fallback: per-batch, single S buffer (33.5 MB), still in-place
    for (int b=0; b<BATCH; b++) {
      score_kernel<<<dim3(32,32,1), 256, 0, stream>>>(Qh, Kh, S, b, 0);
      select_kernel<<<dim3(1024,1), 256, 0, stream>>>(S, 0);
      pv_gemm<<<dim3(2,64,1), 256, 0, stream>>>(Vc, S, out, b, 0);
    }
  }
}